// Round 3
// baseline (416.942 us; speedup 1.0000x reference)
//
#include <hip/hip_runtime.h>
#include <hip/hip_bf16.h>

typedef __attribute__((ext_vector_type(8))) short short8;
typedef __attribute__((ext_vector_type(4))) float f32x4;

#define PADK 1032   // 1024 + 8 pad elements (16B) -> staggered LDS banks

__device__ __forceinline__ float bf2f(unsigned short u) {
    union { unsigned int i; float f; } v; v.i = ((unsigned int)u) << 16; return v.f;
}
__device__ __forceinline__ unsigned short f2bf(float f) {
    __hip_bfloat16 h = __float2bfloat16(f);
    union { __hip_bfloat16 h; unsigned short u; } v; v.h = h; return v.u;
}
__device__ __forceinline__ float gelu_exact(float t) {
    return 0.5f * t * (1.0f + erff(t * 0.70710678118654752f));
}

// ---------------------------------------------------------------------------
// Pack B = [W interleaved | root]  [1152 x 128] into MFMA B-fragment order.
// K-axis permutation: k' = d*8 + r for k'<1024 (d = input dim, r = relation),
// k' = 1024 + d_in for the root part. Fragment:
//   Bfrag[((kb*8 + t)*64 + lane)*8 + j] = B[k'][n],
//   kb=k'>>5, lane=((k'>>3)&3)<<4 | (n&15), j=k'&7, t=n>>4
// ---------------------------------------------------------------------------
__global__ void prep_w(const float* __restrict__ W, const float* __restrict__ root,
                       unsigned short* __restrict__ Bfrag) {
    int i = blockIdx.x * 256 + threadIdx.x;     // over 1152*128
    if (i >= 1152 * 128) return;
    int kp = i >> 7, n = i & 127;
    float v;
    if (kp < 1024) {
        int d = kp >> 3, r = kp & 7;
        v = W[((size_t)r * 128 + d) * 128 + n];
    } else {
        v = root[(size_t)(kp - 1024) * 128 + n];
    }
    int kb = kp >> 5;
    int lane = (((kp >> 3) & 3) << 4) | (n & 15);
    int j = kp & 7;
    int t = n >> 4;
    Bfrag[(((size_t)(kb * 8 + t) * 64 + lane) << 3) + j] = f2bf(v);
}

// ---------------------------------------------------------------------------
// CSR build: zero, histogram, 2-level exclusive scan, scatter (+permuted attr)
// ---------------------------------------------------------------------------
__global__ void zero_i32(int* __restrict__ p, int n) {
    int i = blockIdx.x * 256 + threadIdx.x;
    if (i < n) p[i] = 0;
}

__global__ void hist_dst(const int* __restrict__ ei, int* __restrict__ cnt, int E) {
    int e = blockIdx.x * 256 + threadIdx.x;
    if (e >= E) return;
    atomicAdd(&cnt[ei[E + e]], 1);
}

__global__ void scan1(const int* __restrict__ cnt, int* __restrict__ part,
                      int* __restrict__ bsum, int N) {
    int i = blockIdx.x * 256 + threadIdx.x;
    int v = (i < N) ? cnt[i] : 0;
    int lane = threadIdx.x & 63, wid = threadIdx.x >> 6;
    int s = v;
    #pragma unroll
    for (int off = 1; off < 64; off <<= 1) {
        int t = __shfl_up(s, off);
        if (lane >= off) s += t;
    }
    __shared__ int wsum[4];
    if (lane == 63) wsum[wid] = s;
    __syncthreads();
    int add = 0;
    for (int w = 0; w < wid; ++w) add += wsum[w];
    s += add;
    part[i] = s - v;
    if (threadIdx.x == 255) bsum[blockIdx.x] = s;
}

__global__ void scan2(int* __restrict__ bsum, int nb) {
    int i = threadIdx.x;
    int v = (i < nb) ? bsum[i] : 0;
    int lane = threadIdx.x & 63, wid = threadIdx.x >> 6;
    int s = v;
    #pragma unroll
    for (int off = 1; off < 64; off <<= 1) {
        int t = __shfl_up(s, off);
        if (lane >= off) s += t;
    }
    __shared__ int wsum[4];
    if (lane == 63) wsum[wid] = s;
    __syncthreads();
    int add = 0;
    for (int w = 0; w < wid; ++w) add += wsum[w];
    s += add;
    if (i < nb) bsum[i] = s - v;
}

__global__ void scan3(const int* __restrict__ part, const int* __restrict__ bsum,
                      int* __restrict__ rowptr, int* __restrict__ woff, int N) {
    int i = blockIdx.x * 256 + threadIdx.x;
    if (i >= N) return;
    int v = part[i] + bsum[blockIdx.x];
    rowptr[i] = v;
    woff[i] = v;
}

__global__ void scatter_edges(const int* __restrict__ ei, const float4* __restrict__ attr,
                              int* __restrict__ woff, int* __restrict__ esrc,
                              float4* __restrict__ eattr, int E) {
    int e = blockIdx.x * 256 + threadIdx.x;
    if (e >= E) return;
    int src = ei[e], dst = ei[E + e];
    int p = atomicAdd(&woff[dst], 1);
    esrc[p] = src;
    eattr[2 * p]     = attr[2 * e];
    eattr[2 * p + 1] = attr[2 * e + 1];
}

// ---------------------------------------------------------------------------
// LN + GELU on x (fp32 in) -> y (bf16 out). One wave per row.
// ---------------------------------------------------------------------------
__global__ void ln_gelu(const float* __restrict__ x, const float* __restrict__ g,
                        const float* __restrict__ b, unsigned short* __restrict__ y, int N) {
    int row = (blockIdx.x * blockDim.x + threadIdx.x) >> 6;
    if (row >= N) return;
    int lane = threadIdx.x & 63;
    size_t off = (size_t)row * 128 + lane * 2;
    float2 v = *(const float2*)(x + off);
    float s = v.x + v.y;
    #pragma unroll
    for (int o = 32; o; o >>= 1) s += __shfl_xor(s, o);
    float mu = s * (1.0f / 128.0f);
    float d0 = v.x - mu, d1 = v.y - mu;
    float q = d0 * d0 + d1 * d1;
    #pragma unroll
    for (int o = 32; o; o >>= 1) q += __shfl_xor(q, o);
    float rs = rsqrtf(q * (1.0f / 128.0f) + 1e-5f);
    float2 gg = *(const float2*)(g + lane * 2);
    float2 bb = *(const float2*)(b + lane * 2);
    ushort2 o2;
    o2.x = f2bf(gelu_exact(d0 * rs * gg.x + bb.x));
    o2.y = f2bf(gelu_exact(d1 * rs * gg.y + bb.y));
    *(ushort2*)(y + off) = o2;
}

// ---------------------------------------------------------------------------
// Fused edge-aggregation + GEMM + epilogue. One block = 16 dst nodes.
// Phase 1: wave w aggregates nodes m0+4w..m0+4w+3 into registers
//          (z-row in k'-order: lane holds cols k' = lane*16 .. lane*16+15),
//          writes bf16 A-tile rows to LDS (2x ds_write_b128 per node).
// Phase 2: 4 waves compute [A(16x1024 LDS) | y(16x128 global)] @ B -> 16x128.
//          Wave w owns n-tiles {2w, 2w+1}. Block reads each B-frag exactly once.
// Epilogue MODE 0: +bias -> LN (cross-wave partials in LDS) -> GELU -> bf16.
//          MODE 1: +bias +x residual -> fp32 out.
// ---------------------------------------------------------------------------
template <int MODE>
__global__ __launch_bounds__(256) void edge_gemm(
        const int* __restrict__ rowptr, const int* __restrict__ esrc,
        const float4* __restrict__ eattr, const unsigned short* __restrict__ y,
        const unsigned short* __restrict__ Bfrag, const float* __restrict__ bias,
        const float* __restrict__ lng, const float* __restrict__ lnb,
        const float* __restrict__ xres, void* __restrict__ outp, int N, int E) {
    __shared__ unsigned short Atile[16 * PADK];   // 33,024 B
    __shared__ float2 part[16][4];

    int w = threadIdx.x >> 6;
    int lane = threadIdx.x & 63;
    int m0 = blockIdx.x << 4;

    // ---- phase 1 ----
    #pragma unroll 1
    for (int i = 0; i < 4; ++i) {
        int lrow = w * 4 + i;
        int row = m0 + lrow;
        float a0[8] = {0.f,0.f,0.f,0.f,0.f,0.f,0.f,0.f};
        float a1[8] = {0.f,0.f,0.f,0.f,0.f,0.f,0.f,0.f};
        if (row < N) {
            int e0 = rowptr[row];
            int e1 = (row + 1 < N) ? rowptr[row + 1] : E;
            for (int e = e0; e < e1; ++e) {
                int src = esrc[e];
                float4 w0 = eattr[2 * e];
                float4 w1 = eattr[2 * e + 1];
                unsigned int h = *(const unsigned int*)(y + (size_t)src * 128 + lane * 2);
                float y0 = bf2f((unsigned short)(h & 0xffffu));
                float y1 = bf2f((unsigned short)(h >> 16));
                a0[0] += w0.x * y0; a1[0] += w0.x * y1;
                a0[1] += w0.y * y0; a1[1] += w0.y * y1;
                a0[2] += w0.z * y0; a1[2] += w0.z * y1;
                a0[3] += w0.w * y0; a1[3] += w0.w * y1;
                a0[4] += w1.x * y0; a1[4] += w1.x * y1;
                a0[5] += w1.y * y0; a1[5] += w1.y * y1;
                a0[6] += w1.z * y0; a1[6] += w1.z * y1;
                a0[7] += w1.w * y0; a1[7] += w1.w * y1;
            }
        }
        // k' = d*8 + r: lane's 16 values are contiguous at col lane*16
        short8 p0, p1;
        #pragma unroll
        for (int r = 0; r < 8; ++r) {
            p0[r] = (short)f2bf(a0[r]);
            p1[r] = (short)f2bf(a1[r]);
        }
        unsigned short* dst = &Atile[lrow * PADK + lane * 16];
        *(short8*)dst = p0;
        *(short8*)(dst + 8) = p1;
    }
    __syncthreads();

    // ---- phase 2 ----
    int l15 = lane & 15, lhi = lane >> 4;
    int nt0 = 2 * w, nt1 = 2 * w + 1;
    const short8* bf = (const short8*)Bfrag + lane;
    const unsigned short* arow = &Atile[l15 * PADK + lhi * 8];
    f32x4 acc0 = {0,0,0,0}, acc1 = {0,0,0,0};
    #pragma unroll 4
    for (int kb = 0; kb < 32; ++kb) {
        short8 a = *(const short8*)(arow + kb * 32);
        acc0 = __builtin_amdgcn_mfma_f32_16x16x32_bf16(a, bf[(kb * 8 + nt0) * 64], acc0, 0, 0, 0);
        acc1 = __builtin_amdgcn_mfma_f32_16x16x32_bf16(a, bf[(kb * 8 + nt1) * 64], acc1, 0, 0, 0);
    }
    const unsigned short* ya = y + (size_t)(m0 + l15) * 128 + lhi * 8;
    #pragma unroll
    for (int kb = 32; kb < 36; ++kb) {
        short8 a = *(const short8*)(ya + (kb - 32) * 32);
        acc0 = __builtin_amdgcn_mfma_f32_16x16x32_bf16(a, bf[(kb * 8 + nt0) * 64], acc0, 0, 0, 0);
        acc1 = __builtin_amdgcn_mfma_f32_16x16x32_bf16(a, bf[(kb * 8 + nt1) * 64], acc1, 0, 0, 0);
    }

    float bc0 = bias[nt0 * 16 + l15], bc1 = bias[nt1 * 16 + l15];

    if (MODE == 0) {
        float tv0[4], tv1[4];
        #pragma unroll
        for (int reg = 0; reg < 4; ++reg) {
            tv0[reg] = acc0[reg] + bc0;
            tv1[reg] = acc1[reg] + bc1;
            float s = tv0[reg] + tv1[reg];
            float q = tv0[reg] * tv0[reg] + tv1[reg] * tv1[reg];
            #pragma unroll
            for (int m = 1; m < 16; m <<= 1) {
                s += __shfl_xor(s, m);
                q += __shfl_xor(q, m);
            }
            if (l15 == 0) part[lhi * 4 + reg][w] = make_float2(s, q);
        }
        __syncthreads();
        float g0 = lng[nt0 * 16 + l15], g1 = lng[nt1 * 16 + l15];
        float lb0 = lnb[nt0 * 16 + l15], lb1 = lnb[nt1 * 16 + l15];
        unsigned short* out = (unsigned short*)outp;
        #pragma unroll
        for (int reg = 0; reg < 4; ++reg) {
            int r = lhi * 4 + reg;
            float2 pA = part[r][0], pB = part[r][1], pC = part[r][2], pD = part[r][3];
            float S = pA.x + pB.x + pC.x + pD.x;
            float Q = pA.y + pB.y + pC.y + pD.y;
            float mu = S * (1.0f / 128.0f);
            float var = Q * (1.0f / 128.0f) - mu * mu;
            float rs = rsqrtf(var + 1e-5f);
            int row = m0 + r;
            if (row < N) {
                out[(size_t)row * 128 + nt0 * 16 + l15] = f2bf(gelu_exact((tv0[reg] - mu) * rs * g0 + lb0));
                out[(size_t)row * 128 + nt1 * 16 + l15] = f2bf(gelu_exact((tv1[reg] - mu) * rs * g1 + lb1));
            }
        }
    } else {
        float* out = (float*)outp;
        #pragma unroll
        for (int reg = 0; reg < 4; ++reg) {
            int row = m0 + lhi * 4 + reg;
            if (row < N) {
                size_t i0 = (size_t)row * 128 + nt0 * 16 + l15;
                size_t i1 = (size_t)row * 128 + nt1 * 16 + l15;
                out[i0] = acc0[reg] + bc0 + xres[i0];
                out[i1] = acc1[reg] + bc1 + xres[i1];
            }
        }
    }
}

extern "C" void kernel_launch(void* const* d_in, const int* in_sizes, int n_in,
                              void* d_out, int out_size, void* d_ws, size_t ws_size,
                              hipStream_t stream) {
    const float* x     = (const float*)d_in[0];
    const int*   ei    = (const int*)d_in[1];
    const float* attr  = (const float*)d_in[2];
    const float* ln1g  = (const float*)d_in[3];
    const float* ln1b  = (const float*)d_in[4];
    const float* W1    = (const float*)d_in[5];
    const float* root1 = (const float*)d_in[6];
    const float* b1    = (const float*)d_in[7];
    const float* ln2g  = (const float*)d_in[8];
    const float* ln2b  = (const float*)d_in[9];
    const float* W2    = (const float*)d_in[10];
    const float* root2 = (const float*)d_in[11];
    const float* b2    = (const float*)d_in[12];

    const int N = in_sizes[0] / 128;   // 50000
    const int E = in_sizes[1] / 2;     // 600000

    char* ws = (char*)d_ws;
    unsigned short* y1    = (unsigned short*)(ws);                    // 12,800,000
    unsigned short* y2    = (unsigned short*)(ws + 12800000);         // 12,800,000
    unsigned short* Bf1   = (unsigned short*)(ws + 25600000);         // 294,912
    unsigned short* Bf2   = (unsigned short*)(ws + 25894912);         // 294,912
    int*            cnt   = (int*)(ws + 26189824);                    // 200,704
    int*            part  = (int*)(ws + 26390528);                    // 200,704
    int*            bsum  = (int*)(ws + 26591232);                    // 1,024
    int*            rowptr= (int*)(ws + 26592256);                    // 200,000
    int*            woff  = (int*)(ws + 26792256);                    // 200,000
    int*            esrc  = (int*)(ws + 26992256);                    // 2,400,000
    float4*         eattr = (float4*)(ws + 29392256);                 // 19,200,000

    const int scanBlocks  = (N + 255) / 256;               // 196
    const int edgeBlocksE = (E + 255) / 256;               // 2344
    const int rowsBlocks  = (N * 64 + 255) / 256;          // 12500
    const int fuseBlocks  = (N + 15) / 16;                 // 3125

    // weights -> fragment order
    prep_w<<<576, 256, 0, stream>>>(W1, root1, Bf1);
    prep_w<<<576, 256, 0, stream>>>(W2, root2, Bf2);

    // CSR build (by dst)
    zero_i32<<<scanBlocks, 256, 0, stream>>>(cnt, scanBlocks * 256);
    hist_dst<<<edgeBlocksE, 256, 0, stream>>>(ei, cnt, E);
    scan1<<<scanBlocks, 256, 0, stream>>>(cnt, part, bsum, N);
    scan2<<<1, 256, 0, stream>>>(bsum, scanBlocks);
    scan3<<<scanBlocks, 256, 0, stream>>>(part, bsum, rowptr, woff, N);
    scatter_edges<<<edgeBlocksE, 256, 0, stream>>>(ei, (const float4*)attr, woff, esrc, eattr, E);

    // ---- layer 1 ----
    ln_gelu<<<rowsBlocks, 256, 0, stream>>>(x, ln1g, ln1b, y1, N);
    edge_gemm<0><<<fuseBlocks, 256, 0, stream>>>(rowptr, esrc, eattr, y1, Bf1, b1,
                                                 ln2g, ln2b, nullptr, (void*)y2, N, E);

    // ---- layer 2 ----
    edge_gemm<1><<<fuseBlocks, 256, 0, stream>>>(rowptr, esrc, eattr, y2, Bf2, b2,
                                                 nullptr, nullptr, x, d_out, N, E);
}

// Round 4
// 311.231 us; speedup vs baseline: 1.3397x; 1.3397x over previous
//
#include <hip/hip_runtime.h>
#include <hip/hip_bf16.h>

typedef __attribute__((ext_vector_type(8))) short short8;
typedef __attribute__((ext_vector_type(4))) float f32x4;

__device__ __forceinline__ float bf2f(unsigned short u) {
    union { unsigned int i; float f; } v; v.i = ((unsigned int)u) << 16; return v.f;
}
__device__ __forceinline__ unsigned short f2bf(float f) {
    __hip_bfloat16 h = __float2bfloat16(f);
    union { __hip_bfloat16 h; unsigned short u; } v; v.h = h; return v.u;
}
__device__ __forceinline__ float gelu_exact(float t) {
    return 0.5f * t * (1.0f + erff(t * 0.70710678118654752f));
}
__device__ __forceinline__ short8 ntload8(const unsigned short* p) {
    return __builtin_nontemporal_load((const short8*)p);
}

// ---------------------------------------------------------------------------
// Pack B = [W | root] (1152 x 128) into MFMA B-fragment order with K-axis
// permutation k' = d*8 + r (d = input dim, r = relation); k' = 1024 + d for root.
//   Bfrag[((kb*8 + t)*64 + lane)*8 + j] = B[k'][n]
//   kb = k'>>5, lane = ((k'>>3)&3)<<4 | (n&15), j = k'&7, t = n>>4
// ---------------------------------------------------------------------------
__global__ void prep_w(const float* __restrict__ W, const float* __restrict__ root,
                       unsigned short* __restrict__ Bfrag) {
    int i = blockIdx.x * 256 + threadIdx.x;
    if (i >= 1152 * 128) return;
    int kp = i >> 7, n = i & 127;
    float v;
    if (kp < 1024) {
        int d = kp >> 3, r = kp & 7;
        v = W[((size_t)r * 128 + d) * 128 + n];
    } else {
        v = root[(size_t)(kp - 1024) * 128 + n];
    }
    int kb = kp >> 5;
    int lane = (((kp >> 3) & 3) << 4) | (n & 15);
    int j = kp & 7;
    int t = n >> 4;
    Bfrag[(((size_t)(kb * 8 + t) * 64 + lane) << 3) + j] = f2bf(v);
}

// ---------------------------------------------------------------------------
// CSR build
// ---------------------------------------------------------------------------
__global__ void zero_i32(int* __restrict__ p, int n) {
    int i = blockIdx.x * 256 + threadIdx.x;
    if (i < n) p[i] = 0;
}

__global__ void hist_dst(const int* __restrict__ ei, int* __restrict__ cnt, int E) {
    int e = blockIdx.x * 256 + threadIdx.x;
    if (e >= E) return;
    atomicAdd(&cnt[ei[E + e]], 1);
}

__global__ void scan1(const int* __restrict__ cnt, int* __restrict__ part,
                      int* __restrict__ bsum, int N) {
    int i = blockIdx.x * 256 + threadIdx.x;
    int v = (i < N) ? cnt[i] : 0;
    int lane = threadIdx.x & 63, wid = threadIdx.x >> 6;
    int s = v;
    #pragma unroll
    for (int off = 1; off < 64; off <<= 1) {
        int t = __shfl_up(s, off);
        if (lane >= off) s += t;
    }
    __shared__ int wsum[4];
    if (lane == 63) wsum[wid] = s;
    __syncthreads();
    int add = 0;
    for (int w = 0; w < wid; ++w) add += wsum[w];
    s += add;
    part[i] = s - v;
    if (threadIdx.x == 255) bsum[blockIdx.x] = s;
}

__global__ void scan2(int* __restrict__ bsum, int nb) {
    int i = threadIdx.x;
    int v = (i < nb) ? bsum[i] : 0;
    int lane = threadIdx.x & 63, wid = threadIdx.x >> 6;
    int s = v;
    #pragma unroll
    for (int off = 1; off < 64; off <<= 1) {
        int t = __shfl_up(s, off);
        if (lane >= off) s += t;
    }
    __shared__ int wsum[4];
    if (lane == 63) wsum[wid] = s;
    __syncthreads();
    int add = 0;
    for (int w = 0; w < wid; ++w) add += wsum[w];
    s += add;
    if (i < nb) bsum[i] = s - v;
}

__global__ void scan3(const int* __restrict__ part, const int* __restrict__ bsum,
                      int* __restrict__ rowptr, int* __restrict__ woff, int N) {
    int i = blockIdx.x * 256 + threadIdx.x;
    if (i >= N) return;
    int v = part[i] + bsum[blockIdx.x];
    rowptr[i] = v;
    woff[i] = v;
}

__global__ void scatter_edges(const int* __restrict__ ei, const float4* __restrict__ attr,
                              int* __restrict__ woff, int* __restrict__ esrc,
                              float4* __restrict__ eattr, int E) {
    int e = blockIdx.x * 256 + threadIdx.x;
    if (e >= E) return;
    int src = ei[e], dst = ei[E + e];
    int p = atomicAdd(&woff[dst], 1);
    esrc[p] = src;
    eattr[2 * p]     = attr[2 * e];
    eattr[2 * p + 1] = attr[2 * e + 1];
}

// ---------------------------------------------------------------------------
// LN + GELU on x (fp32 in) -> y (bf16 out). One wave per row.
// ---------------------------------------------------------------------------
__global__ void ln_gelu(const float* __restrict__ x, const float* __restrict__ g,
                        const float* __restrict__ b, unsigned short* __restrict__ y, int N) {
    int row = (blockIdx.x * blockDim.x + threadIdx.x) >> 6;
    if (row >= N) return;
    int lane = threadIdx.x & 63;
    size_t off = (size_t)row * 128 + lane * 2;
    float2 v = *(const float2*)(x + off);
    float s = v.x + v.y;
    #pragma unroll
    for (int o = 32; o; o >>= 1) s += __shfl_xor(s, o);
    float mu = s * (1.0f / 128.0f);
    float d0 = v.x - mu, d1 = v.y - mu;
    float q = d0 * d0 + d1 * d1;
    #pragma unroll
    for (int o = 32; o; o >>= 1) q += __shfl_xor(q, o);
    float rs = rsqrtf(q * (1.0f / 128.0f) + 1e-5f);
    float2 gg = *(const float2*)(g + lane * 2);
    float2 bb = *(const float2*)(b + lane * 2);
    ushort2 o2;
    o2.x = f2bf(gelu_exact(d0 * rs * gg.x + bb.x));
    o2.y = f2bf(gelu_exact(d1 * rs * gg.y + bb.y));
    *(ushort2*)(y + off) = o2;
}

// ---------------------------------------------------------------------------
// Edge aggregation into z (k'-ordered: z[v][lane*16 + c] covers d=2*lane(+1),
// r=0..7). One wave per dst node; edge loop unrolled x4 so 4 y-gathers are in
// flight. Output: one contiguous 32B nt-store per lane.
// ---------------------------------------------------------------------------
__global__ __launch_bounds__(256) void edge_z(const int* __restrict__ rowptr,
                                              const int* __restrict__ esrc,
                                              const float4* __restrict__ eattr,
                                              const unsigned short* __restrict__ y,
                                              unsigned short* __restrict__ z, int N, int E) {
    int row = (blockIdx.x << 2) + (threadIdx.x >> 6);
    if (row >= N) return;
    int lane = threadIdx.x & 63;
    int e0 = rowptr[row];
    int e1 = (row + 1 < N) ? rowptr[row + 1] : E;
    float a0[8] = {0,0,0,0,0,0,0,0};
    float a1[8] = {0,0,0,0,0,0,0,0};

    const unsigned short* yl = y + lane * 2;

    int e = e0;
    for (; e + 4 <= e1; e += 4) {
        int s0 = esrc[e], s1 = esrc[e + 1], s2 = esrc[e + 2], s3 = esrc[e + 3];
        float4 wA0 = eattr[2 * e],     wA1 = eattr[2 * e + 1];
        float4 wB0 = eattr[2 * e + 2], wB1 = eattr[2 * e + 3];
        float4 wC0 = eattr[2 * e + 4], wC1 = eattr[2 * e + 5];
        float4 wD0 = eattr[2 * e + 6], wD1 = eattr[2 * e + 7];
        unsigned int h0 = *(const unsigned int*)(yl + (size_t)s0 * 128);
        unsigned int h1 = *(const unsigned int*)(yl + (size_t)s1 * 128);
        unsigned int h2 = *(const unsigned int*)(yl + (size_t)s2 * 128);
        unsigned int h3 = *(const unsigned int*)(yl + (size_t)s3 * 128);
        float y00 = bf2f((unsigned short)(h0 & 0xffffu)), y01 = bf2f((unsigned short)(h0 >> 16));
        float y10 = bf2f((unsigned short)(h1 & 0xffffu)), y11 = bf2f((unsigned short)(h1 >> 16));
        float y20 = bf2f((unsigned short)(h2 & 0xffffu)), y21 = bf2f((unsigned short)(h2 >> 16));
        float y30 = bf2f((unsigned short)(h3 & 0xffffu)), y31 = bf2f((unsigned short)(h3 >> 16));
        a0[0] += wA0.x * y00; a1[0] += wA0.x * y01;
        a0[1] += wA0.y * y00; a1[1] += wA0.y * y01;
        a0[2] += wA0.z * y00; a1[2] += wA0.z * y01;
        a0[3] += wA0.w * y00; a1[3] += wA0.w * y01;
        a0[4] += wA1.x * y00; a1[4] += wA1.x * y01;
        a0[5] += wA1.y * y00; a1[5] += wA1.y * y01;
        a0[6] += wA1.z * y00; a1[6] += wA1.z * y01;
        a0[7] += wA1.w * y00; a1[7] += wA1.w * y01;
        a0[0] += wB0.x * y10; a1[0] += wB0.x * y11;
        a0[1] += wB0.y * y10; a1[1] += wB0.y * y11;
        a0[2] += wB0.z * y10; a1[2] += wB0.z * y11;
        a0[3] += wB0.w * y10; a1[3] += wB0.w * y11;
        a0[4] += wB1.x * y10; a1[4] += wB1.x * y11;
        a0[5] += wB1.y * y10; a1[5] += wB1.y * y11;
        a0[6] += wB1.z * y10; a1[6] += wB1.z * y11;
        a0[7] += wB1.w * y10; a1[7] += wB1.w * y11;
        a0[0] += wC0.x * y20; a1[0] += wC0.x * y21;
        a0[1] += wC0.y * y20; a1[1] += wC0.y * y21;
        a0[2] += wC0.z * y20; a1[2] += wC0.z * y21;
        a0[3] += wC0.w * y20; a1[3] += wC0.w * y21;
        a0[4] += wC1.x * y20; a1[4] += wC1.x * y21;
        a0[5] += wC1.y * y20; a1[5] += wC1.y * y21;
        a0[6] += wC1.z * y20; a1[6] += wC1.z * y21;
        a0[7] += wC1.w * y20; a1[7] += wC1.w * y21;
        a0[0] += wD0.x * y30; a1[0] += wD0.x * y31;
        a0[1] += wD0.y * y30; a1[1] += wD0.y * y31;
        a0[2] += wD0.z * y30; a1[2] += wD0.z * y31;
        a0[3] += wD0.w * y30; a1[3] += wD0.w * y31;
        a0[4] += wD1.x * y30; a1[4] += wD1.x * y31;
        a0[5] += wD1.y * y30; a1[5] += wD1.y * y31;
        a0[6] += wD1.z * y30; a1[6] += wD1.z * y31;
        a0[7] += wD1.w * y30; a1[7] += wD1.w * y31;
    }
    for (; e < e1; ++e) {
        int src = esrc[e];
        float4 w0 = eattr[2 * e], w1 = eattr[2 * e + 1];
        unsigned int h = *(const unsigned int*)(yl + (size_t)src * 128);
        float y0 = bf2f((unsigned short)(h & 0xffffu)), y1 = bf2f((unsigned short)(h >> 16));
        a0[0] += w0.x * y0; a1[0] += w0.x * y1;
        a0[1] += w0.y * y0; a1[1] += w0.y * y1;
        a0[2] += w0.z * y0; a1[2] += w0.z * y1;
        a0[3] += w0.w * y0; a1[3] += w0.w * y1;
        a0[4] += w1.x * y0; a1[4] += w1.x * y1;
        a0[5] += w1.y * y0; a1[5] += w1.y * y1;
        a0[6] += w1.z * y0; a1[6] += w1.z * y1;
        a0[7] += w1.w * y0; a1[7] += w1.w * y1;
    }
    short8 p0, p1;
    #pragma unroll
    for (int r = 0; r < 8; ++r) {
        p0[r] = (short)f2bf(a0[r]);
        p1[r] = (short)f2bf(a1[r]);
    }
    unsigned short* zr = z + (size_t)row * 1024 + lane * 16;
    __builtin_nontemporal_store(p0, (short8*)zr);
    __builtin_nontemporal_store(p1, (short8*)(zr + 8));
}

// ---------------------------------------------------------------------------
// GEMM: [z | y] (N x 1152, k'-ordered) @ B (1152 x 128) with B staged per-kb
// slice (8KB) in double-buffered LDS via global_load_lds, shared by 4 waves.
// Each wave owns 16 rows (full 128 output cols, 8 n-tiles). A-frags register-
// prefetched one kb ahead. Epilogue fused (wave-local, 16-lane LN reduce).
// MODE 0: gelu(LN(C+bias)) -> bf16.  MODE 1: C+bias+xres -> fp32.
// ---------------------------------------------------------------------------
template <int MODE>
__global__ __launch_bounds__(256) void gemm_fused(
        const unsigned short* __restrict__ z, const unsigned short* __restrict__ y,
        const unsigned short* __restrict__ Bfrag, const float* __restrict__ bias,
        const float* __restrict__ lng, const float* __restrict__ lnb,
        const float* __restrict__ xres, void* __restrict__ outp, int N) {
    __shared__ short8 Bs[2][512];   // 2 x 8KB

    int w = threadIdx.x >> 6;
    int lane = threadIdx.x & 63;
    int l15 = lane & 15, lhi = lane >> 4;
    int m0 = (blockIdx.x * 4 + w) << 4;       // this wave's 16-row tile

    const unsigned short* za = z + (size_t)(m0 + l15) * 1024 + lhi * 8;
    const unsigned short* ya = y + (size_t)(m0 + l15) * 128 + lhi * 8;
    const short8* bfb = (const short8*)Bfrag;

    // stage B slice for kb into Bs[buf]: 8KB, 2 global_load_lds(16B) per thread
    #define STAGE(buf, kb)                                                         \
        do {                                                                       \
            const short8* gsrc = bfb + (kb) * 512 + w * 128;                       \
            __builtin_amdgcn_global_load_lds(&gsrc[lane],      &Bs[buf][w * 128],      16, 0, 0); \
            __builtin_amdgcn_global_load_lds(&gsrc[64 + lane], &Bs[buf][w * 128 + 64], 16, 0, 0); \
        } while (0)

    STAGE(0, 0);
    short8 a_cur = ntload8(za);
    __syncthreads();

    f32x4 acc[8] = {};
    for (int kb = 0; kb < 36; ++kb) {
        int cur = kb & 1;
        short8 a_next;
        if (kb + 1 < 36) {
            STAGE(cur ^ 1, kb + 1);
            a_next = (kb + 1 < 32) ? ntload8(za + (kb + 1) * 32)
                                   : ntload8(ya + (kb + 1 - 32) * 32);
        }
        #pragma unroll
        for (int t = 0; t < 8; ++t) {
            short8 b = Bs[cur][t * 64 + lane];
            acc[t] = __builtin_amdgcn_mfma_f32_16x16x32_bf16(a_cur, b, acc[t], 0, 0, 0);
        }
        __syncthreads();      // drains next-stage vmcnt + protects buffer reuse
        a_cur = a_next;
    }
    #undef STAGE

    float bcol[8];
    #pragma unroll
    for (int t = 0; t < 8; ++t) bcol[t] = bias[t * 16 + l15];

    if (MODE == 0) {
        float gcol[8], lbcol[8];
        #pragma unroll
        for (int t = 0; t < 8; ++t) { gcol[t] = lng[t * 16 + l15]; lbcol[t] = lnb[t * 16 + l15]; }
        unsigned short* out = (unsigned short*)outp;
        #pragma unroll
        for (int reg = 0; reg < 4; ++reg) {
            int row = m0 + lhi * 4 + reg;
            float tv[8];
            float s = 0.f;
            #pragma unroll
            for (int t = 0; t < 8; ++t) { tv[t] = acc[t][reg] + bcol[t]; s += tv[t]; }
            #pragma unroll
            for (int msk = 1; msk < 16; msk <<= 1) s += __shfl_xor(s, msk);
            float mu = s * (1.0f / 128.0f);
            float q = 0.f;
            #pragma unroll
            for (int t = 0; t < 8; ++t) { float d = tv[t] - mu; q += d * d; }
            #pragma unroll
            for (int msk = 1; msk < 16; msk <<= 1) q += __shfl_xor(q, msk);
            float rs = rsqrtf(q * (1.0f / 128.0f) + 1e-5f);
            if (row < N) {
                #pragma unroll
                for (int t = 0; t < 8; ++t) {
                    float u = gelu_exact((tv[t] - mu) * rs * gcol[t] + lbcol[t]);
                    out[(size_t)row * 128 + t * 16 + l15] = f2bf(u);
                }
            }
        }
    } else {
        float* out = (float*)outp;
        #pragma unroll
        for (int reg = 0; reg < 4; ++reg) {
            int row = m0 + lhi * 4 + reg;
            if (row < N) {
                #pragma unroll
                for (int t = 0; t < 8; ++t) {
                    size_t idx = (size_t)row * 128 + t * 16 + l15;
                    out[idx] = acc[t][reg] + bcol[t] + xres[idx];
                }
            }
        }
    }
}

extern "C" void kernel_launch(void* const* d_in, const int* in_sizes, int n_in,
                              void* d_out, int out_size, void* d_ws, size_t ws_size,
                              hipStream_t stream) {
    const float* x     = (const float*)d_in[0];
    const int*   ei    = (const int*)d_in[1];
    const float* attr  = (const float*)d_in[2];
    const float* ln1g  = (const float*)d_in[3];
    const float* ln1b  = (const float*)d_in[4];
    const float* W1    = (const float*)d_in[5];
    const float* root1 = (const float*)d_in[6];
    const float* b1    = (const float*)d_in[7];
    const float* ln2g  = (const float*)d_in[8];
    const float* ln2b  = (const float*)d_in[9];
    const float* W2    = (const float*)d_in[10];
    const float* root2 = (const float*)d_in[11];
    const float* b2    = (const float*)d_in[12];

    const int N = in_sizes[0] / 128;   // 50000
    const int E = in_sizes[1] / 2;     // 600000

    // workspace layout (all offsets multiple of 16; y/z padded +64 rows for
    // the last GEMM block's OOB-safe reads)
    char* ws = (char*)d_ws;
    unsigned short* y1    = (unsigned short*)(ws);                    // 12,812,288 (+pad)
    unsigned short* y2    = (unsigned short*)(ws + 12900000);         // 12,812,288 (+pad)
    unsigned short* z     = (unsigned short*)(ws + 25800000);         // 102,498,304 (+pad)
    unsigned short* Bf1   = (unsigned short*)(ws + 128400000);        // 294,912
    unsigned short* Bf2   = (unsigned short*)(ws + 128700000);        // 294,912
    int*            cnt   = (int*)(ws + 129000000);                   // 200,704
    int*            part  = (int*)(ws + 129210000);                   // 200,704
    int*            bsum  = (int*)(ws + 129420000);                   // 1,024
    int*            rowptr= (int*)(ws + 129430000);                   // 200,000
    int*            woff  = (int*)(ws + 129640000);                   // 200,000
    int*            esrc  = (int*)(ws + 129850000);                   // 2,400,000
    float4*         eattr = (float4*)(ws + 132250000);                // 19,200,000

    const int scanBlocks  = (N + 255) / 256;               // 196
    const int edgeBlocksE = (E + 255) / 256;               // 2344
    const int rowsBlocks  = (N * 64 + 255) / 256;          // 12500
    const int nodeBlocks  = (N + 3) / 4;                   // 12500
    const int gemmBlocks  = (N + 63) / 64;                 // 782

    // weights -> fragment order
    prep_w<<<576, 256, 0, stream>>>(W1, root1, Bf1);
    prep_w<<<576, 256, 0, stream>>>(W2, root2, Bf2);

    // CSR build (by dst)
    zero_i32<<<scanBlocks, 256, 0, stream>>>(cnt, scanBlocks * 256);
    hist_dst<<<edgeBlocksE, 256, 0, stream>>>(ei, cnt, E);
    scan1<<<scanBlocks, 256, 0, stream>>>(cnt, part, bsum, N);
    scan2<<<1, 256, 0, stream>>>(bsum, scanBlocks);
    scan3<<<scanBlocks, 256, 0, stream>>>(part, bsum, rowptr, woff, N);
    scatter_edges<<<edgeBlocksE, 256, 0, stream>>>(ei, (const float4*)attr, woff, esrc, eattr, E);

    // ---- layer 1 ----
    ln_gelu<<<rowsBlocks, 256, 0, stream>>>(x, ln1g, ln1b, y1, N);
    edge_z<<<nodeBlocks, 256, 0, stream>>>(rowptr, esrc, eattr, y1, z, N, E);
    gemm_fused<0><<<gemmBlocks, 256, 0, stream>>>(z, y1, Bf1, b1, ln2g, ln2b, nullptr, (void*)y2, N);

    // ---- layer 2 ----
    edge_z<<<nodeBlocks, 256, 0, stream>>>(rowptr, esrc, eattr, y2, z, N, E);
    gemm_fused<1><<<gemmBlocks, 256, 0, stream>>>(z, y2, Bf2, b2, nullptr, nullptr, x, d_out, N);
}

// Round 5
// 302.283 us; speedup vs baseline: 1.3793x; 1.0296x over previous
//
#include <hip/hip_runtime.h>
#include <hip/hip_bf16.h>

typedef __attribute__((ext_vector_type(8))) short short8;
typedef __attribute__((ext_vector_type(4))) float f32x4;

__device__ __forceinline__ float bf2f(unsigned short u) {
    union { unsigned int i; float f; } v; v.i = ((unsigned int)u) << 16; return v.f;
}
__device__ __forceinline__ unsigned short f2bf(float f) {
    __hip_bfloat16 h = __float2bfloat16(f);
    union { __hip_bfloat16 h; unsigned short u; } v; v.h = h; return v.u;
}
__device__ __forceinline__ float gelu_exact(float t) {
    return 0.5f * t * (1.0f + erff(t * 0.70710678118654752f));
}
__device__ __forceinline__ short8 ntload8(const unsigned short* p) {
    return __builtin_nontemporal_load((const short8*)p);
}

// ---------------------------------------------------------------------------
// Pack B = [W | root] (1152 x 128) into MFMA B-fragment order with K-axis
// permutation k' = d*8 + r (d = input dim, r = relation); k' = 1024 + d for root.
//   Bfrag[((kb*8 + t)*64 + lane)*8 + j] = B[k'][n]
//   kb = k'>>5, lane = ((k'>>3)&3)<<4 | (n&15), j = k'&7, t = n>>4
// Both layers in one launch: i >= 1152*128 -> layer 2.
// ---------------------------------------------------------------------------
__global__ void prep_w(const float* __restrict__ W1, const float* __restrict__ root1,
                       unsigned short* __restrict__ Bf1,
                       const float* __restrict__ W2, const float* __restrict__ root2,
                       unsigned short* __restrict__ Bf2) {
    int i = blockIdx.x * 256 + threadIdx.x;
    const float* W = W1; const float* root = root1; unsigned short* Bfrag = Bf1;
    if (i >= 1152 * 128) {
        i -= 1152 * 128; W = W2; root = root2; Bfrag = Bf2;
        if (i >= 1152 * 128) return;
    }
    int kp = i >> 7, n = i & 127;
    float v;
    if (kp < 1024) {
        int d = kp >> 3, r = kp & 7;
        v = W[((size_t)r * 128 + d) * 128 + n];
    } else {
        v = root[(size_t)(kp - 1024) * 128 + n];
    }
    int kb = kp >> 5;
    int lane = (((kp >> 3) & 3) << 4) | (n & 15);
    int j = kp & 7;
    int t = n >> 4;
    Bfrag[(((size_t)(kb * 8 + t) * 64 + lane) << 3) + j] = f2bf(v);
}

// ---------------------------------------------------------------------------
// CSR build
// ---------------------------------------------------------------------------
__global__ void zero_i32(int* __restrict__ p, int n) {
    int i = blockIdx.x * 256 + threadIdx.x;
    if (i < n) p[i] = 0;
}

__global__ void hist_dst(const int* __restrict__ ei, int* __restrict__ cnt, int E) {
    int e = blockIdx.x * 256 + threadIdx.x;
    if (e >= E) return;
    atomicAdd(&cnt[ei[E + e]], 1);
}

__global__ void scan1(const int* __restrict__ cnt, int* __restrict__ part,
                      int* __restrict__ bsum, int N) {
    int i = blockIdx.x * 256 + threadIdx.x;
    int v = (i < N) ? cnt[i] : 0;
    int lane = threadIdx.x & 63, wid = threadIdx.x >> 6;
    int s = v;
    #pragma unroll
    for (int off = 1; off < 64; off <<= 1) {
        int t = __shfl_up(s, off);
        if (lane >= off) s += t;
    }
    __shared__ int wsum[4];
    if (lane == 63) wsum[wid] = s;
    __syncthreads();
    int add = 0;
    for (int w = 0; w < wid; ++w) add += wsum[w];
    s += add;
    part[i] = s - v;
    if (threadIdx.x == 255) bsum[blockIdx.x] = s;
}

__global__ void scan2(int* __restrict__ bsum, int nb) {
    int i = threadIdx.x;
    int v = (i < nb) ? bsum[i] : 0;
    int lane = threadIdx.x & 63, wid = threadIdx.x >> 6;
    int s = v;
    #pragma unroll
    for (int off = 1; off < 64; off <<= 1) {
        int t = __shfl_up(s, off);
        if (lane >= off) s += t;
    }
    __shared__ int wsum[4];
    if (lane == 63) wsum[wid] = s;
    __syncthreads();
    int add = 0;
    for (int w = 0; w < wid; ++w) add += wsum[w];
    s += add;
    if (i < nb) bsum[i] = s - v;
}

__global__ void scan3(const int* __restrict__ part, const int* __restrict__ bsum,
                      int* __restrict__ rowptr, int* __restrict__ woff, int N) {
    int i = blockIdx.x * 256 + threadIdx.x;
    if (i >= N) return;
    int v = part[i] + bsum[blockIdx.x];
    rowptr[i] = v;
    woff[i] = v;
}

__global__ void scatter_edges(const int* __restrict__ ei, const float4* __restrict__ attr,
                              int* __restrict__ woff, int* __restrict__ esrc,
                              float4* __restrict__ eattr, int E) {
    int e = blockIdx.x * 256 + threadIdx.x;
    if (e >= E) return;
    int src = ei[e], dst = ei[E + e];
    int p = atomicAdd(&woff[dst], 1);
    esrc[p] = src;
    eattr[2 * p]     = attr[2 * e];
    eattr[2 * p + 1] = attr[2 * e + 1];
}

// ---------------------------------------------------------------------------
// LN + GELU on x (fp32 in) -> y (bf16 out). One wave per row.
// ---------------------------------------------------------------------------
__global__ void ln_gelu(const float* __restrict__ x, const float* __restrict__ g,
                        const float* __restrict__ b, unsigned short* __restrict__ y, int N) {
    int row = (blockIdx.x * blockDim.x + threadIdx.x) >> 6;
    if (row >= N) return;
    int lane = threadIdx.x & 63;
    size_t off = (size_t)row * 128 + lane * 2;
    float2 v = *(const float2*)(x + off);
    float s = v.x + v.y;
    #pragma unroll
    for (int o = 32; o; o >>= 1) s += __shfl_xor(s, o);
    float mu = s * (1.0f / 128.0f);
    float d0 = v.x - mu, d1 = v.y - mu;
    float q = d0 * d0 + d1 * d1;
    #pragma unroll
    for (int o = 32; o; o >>= 1) q += __shfl_xor(q, o);
    float rs = rsqrtf(q * (1.0f / 128.0f) + 1e-5f);
    float2 gg = *(const float2*)(g + lane * 2);
    float2 bb = *(const float2*)(b + lane * 2);
    ushort2 o2;
    o2.x = f2bf(gelu_exact(d0 * rs * gg.x + bb.x));
    o2.y = f2bf(gelu_exact(d1 * rs * gg.y + bb.y));
    *(ushort2*)(y + off) = o2;
}

// ---------------------------------------------------------------------------
// Edge aggregation into z (k'-ordered). One wave per dst node; edge loop
// unrolled x4 (4 y-gathers in flight). 32B contiguous nt-store per lane.
// ---------------------------------------------------------------------------
__global__ __launch_bounds__(256) void edge_z(const int* __restrict__ rowptr,
                                              const int* __restrict__ esrc,
                                              const float4* __restrict__ eattr,
                                              const unsigned short* __restrict__ y,
                                              unsigned short* __restrict__ z, int N, int E) {
    int row = (blockIdx.x << 2) + (threadIdx.x >> 6);
    if (row >= N) return;
    int lane = threadIdx.x & 63;
    int e0 = rowptr[row];
    int e1 = (row + 1 < N) ? rowptr[row + 1] : E;
    float a0[8] = {0,0,0,0,0,0,0,0};
    float a1[8] = {0,0,0,0,0,0,0,0};

    const unsigned short* yl = y + lane * 2;

    int e = e0;
    for (; e + 4 <= e1; e += 4) {
        int s0 = esrc[e], s1 = esrc[e + 1], s2 = esrc[e + 2], s3 = esrc[e + 3];
        float4 wA0 = eattr[2 * e],     wA1 = eattr[2 * e + 1];
        float4 wB0 = eattr[2 * e + 2], wB1 = eattr[2 * e + 3];
        float4 wC0 = eattr[2 * e + 4], wC1 = eattr[2 * e + 5];
        float4 wD0 = eattr[2 * e + 6], wD1 = eattr[2 * e + 7];
        unsigned int h0 = *(const unsigned int*)(yl + (size_t)s0 * 128);
        unsigned int h1 = *(const unsigned int*)(yl + (size_t)s1 * 128);
        unsigned int h2 = *(const unsigned int*)(yl + (size_t)s2 * 128);
        unsigned int h3 = *(const unsigned int*)(yl + (size_t)s3 * 128);
        float y00 = bf2f((unsigned short)(h0 & 0xffffu)), y01 = bf2f((unsigned short)(h0 >> 16));
        float y10 = bf2f((unsigned short)(h1 & 0xffffu)), y11 = bf2f((unsigned short)(h1 >> 16));
        float y20 = bf2f((unsigned short)(h2 & 0xffffu)), y21 = bf2f((unsigned short)(h2 >> 16));
        float y30 = bf2f((unsigned short)(h3 & 0xffffu)), y31 = bf2f((unsigned short)(h3 >> 16));
        a0[0] += wA0.x * y00; a1[0] += wA0.x * y01;
        a0[1] += wA0.y * y00; a1[1] += wA0.y * y01;
        a0[2] += wA0.z * y00; a1[2] += wA0.z * y01;
        a0[3] += wA0.w * y00; a1[3] += wA0.w * y01;
        a0[4] += wA1.x * y00; a1[4] += wA1.x * y01;
        a0[5] += wA1.y * y00; a1[5] += wA1.y * y01;
        a0[6] += wA1.z * y00; a1[6] += wA1.z * y01;
        a0[7] += wA1.w * y00; a1[7] += wA1.w * y01;
        a0[0] += wB0.x * y10; a1[0] += wB0.x * y11;
        a0[1] += wB0.y * y10; a1[1] += wB0.y * y11;
        a0[2] += wB0.z * y10; a1[2] += wB0.z * y11;
        a0[3] += wB0.w * y10; a1[3] += wB0.w * y11;
        a0[4] += wB1.x * y10; a1[4] += wB1.x * y11;
        a0[5] += wB1.y * y10; a1[5] += wB1.y * y11;
        a0[6] += wB1.z * y10; a1[6] += wB1.z * y11;
        a0[7] += wB1.w * y10; a1[7] += wB1.w * y11;
        a0[0] += wC0.x * y20; a1[0] += wC0.x * y21;
        a0[1] += wC0.y * y20; a1[1] += wC0.y * y21;
        a0[2] += wC0.z * y20; a1[2] += wC0.z * y21;
        a0[3] += wC0.w * y20; a1[3] += wC0.w * y21;
        a0[4] += wC1.x * y20; a1[4] += wC1.x * y21;
        a0[5] += wC1.y * y20; a1[5] += wC1.y * y21;
        a0[6] += wC1.z * y20; a1[6] += wC1.z * y21;
        a0[7] += wC1.w * y20; a1[7] += wC1.w * y21;
        a0[0] += wD0.x * y30; a1[0] += wD0.x * y31;
        a0[1] += wD0.y * y30; a1[1] += wD0.y * y31;
        a0[2] += wD0.z * y30; a1[2] += wD0.z * y31;
        a0[3] += wD0.w * y30; a1[3] += wD0.w * y31;
        a0[4] += wD1.x * y30; a1[4] += wD1.x * y31;
        a0[5] += wD1.y * y30; a1[5] += wD1.y * y31;
        a0[6] += wD1.z * y30; a1[6] += wD1.z * y31;
        a0[7] += wD1.w * y30; a1[7] += wD1.w * y31;
    }
    for (; e < e1; ++e) {
        int src = esrc[e];
        float4 w0 = eattr[2 * e], w1 = eattr[2 * e + 1];
        unsigned int h = *(const unsigned int*)(yl + (size_t)src * 128);
        float y0 = bf2f((unsigned short)(h & 0xffffu)), y1 = bf2f((unsigned short)(h >> 16));
        a0[0] += w0.x * y0; a1[0] += w0.x * y1;
        a0[1] += w0.y * y0; a1[1] += w0.y * y1;
        a0[2] += w0.z * y0; a1[2] += w0.z * y1;
        a0[3] += w0.w * y0; a1[3] += w0.w * y1;
        a0[4] += w1.x * y0; a1[4] += w1.x * y1;
        a0[5] += w1.y * y0; a1[5] += w1.y * y1;
        a0[6] += w1.z * y0; a1[6] += w1.z * y1;
        a0[7] += w1.w * y0; a1[7] += w1.w * y1;
    }
    short8 p0, p1;
    #pragma unroll
    for (int r = 0; r < 8; ++r) {
        p0[r] = (short)f2bf(a0[r]);
        p1[r] = (short)f2bf(a1[r]);
    }
    unsigned short* zr = z + (size_t)row * 1024 + lane * 16;
    __builtin_nontemporal_store(p0, (short8*)zr);
    __builtin_nontemporal_store(p1, (short8*)(zr + 8));
}

// ---------------------------------------------------------------------------
// GEMM v2: [z | y] (N x 1152, k'-ordered) @ B (1152 x 128).
// Wave = 32 rows x 128 cols (two 16-row groups); block = 4 waves = 128 rows.
// B staged per-kb slice (8KB) in double-buffered LDS via global_load_lds
// (block-cooperative), A-frags register-prefetched one kb ahead.
// 16 MFMA per barrier pair (vs 8 in v1) -> half the barrier overhead/row.
// Epilogue fused. MODE 0: gelu(LN(C+bias)) -> bf16.  MODE 1: C+bias+xres -> fp32.
// ---------------------------------------------------------------------------
template <int MODE>
__global__ __launch_bounds__(256) void gemm_fused(
        const unsigned short* __restrict__ z, const unsigned short* __restrict__ y,
        const unsigned short* __restrict__ Bfrag, const float* __restrict__ bias,
        const float* __restrict__ lng, const float* __restrict__ lnb,
        const float* __restrict__ xres, void* __restrict__ outp, int N) {
    __shared__ short8 Bs[2][512];   // 2 x 8KB

    int w = threadIdx.x >> 6;
    int lane = threadIdx.x & 63;
    int l15 = lane & 15, lhi = lane >> 4;
    int m0 = blockIdx.x * 128 + w * 32;       // wave's 32-row tile

    const unsigned short* za0 = z + (size_t)(m0 + l15) * 1024 + lhi * 8;
    const unsigned short* za1 = za0 + (size_t)16 * 1024;
    const unsigned short* ya0 = y + (size_t)(m0 + l15) * 128 + lhi * 8;
    const unsigned short* ya1 = ya0 + 16 * 128;
    const short8* bfb = (const short8*)Bfrag;

    #define STAGE(buf, kb)                                                         \
        do {                                                                       \
            const short8* gsrc = bfb + (kb) * 512 + w * 128;                       \
            __builtin_amdgcn_global_load_lds(&gsrc[lane],      &Bs[buf][w * 128],      16, 0, 0); \
            __builtin_amdgcn_global_load_lds(&gsrc[64 + lane], &Bs[buf][w * 128 + 64], 16, 0, 0); \
        } while (0)

    STAGE(0, 0);
    short8 a0 = ntload8(za0);
    short8 a1 = ntload8(za1);
    __syncthreads();

    f32x4 acc0[8] = {}, acc1[8] = {};
    for (int kb = 0; kb < 36; ++kb) {
        int cur = kb & 1;
        short8 n0, n1;
        if (kb + 1 < 36) {
            STAGE(cur ^ 1, kb + 1);
            if (kb + 1 < 32) {
                n0 = ntload8(za0 + (kb + 1) * 32);
                n1 = ntload8(za1 + (kb + 1) * 32);
            } else {
                n0 = ntload8(ya0 + (kb + 1 - 32) * 32);
                n1 = ntload8(ya1 + (kb + 1 - 32) * 32);
            }
        }
        #pragma unroll
        for (int t = 0; t < 8; ++t) {
            short8 b = Bs[cur][t * 64 + lane];
            acc0[t] = __builtin_amdgcn_mfma_f32_16x16x32_bf16(a0, b, acc0[t], 0, 0, 0);
            acc1[t] = __builtin_amdgcn_mfma_f32_16x16x32_bf16(a1, b, acc1[t], 0, 0, 0);
        }
        __syncthreads();      // drains next-stage vmcnt + protects buffer reuse
        a0 = n0; a1 = n1;
    }
    #undef STAGE

    float bcol[8];
    #pragma unroll
    for (int t = 0; t < 8; ++t) bcol[t] = bias[t * 16 + l15];

    if (MODE == 0) {
        float gcol[8], lbcol[8];
        #pragma unroll
        for (int t = 0; t < 8; ++t) { gcol[t] = lng[t * 16 + l15]; lbcol[t] = lnb[t * 16 + l15]; }
        unsigned short* out = (unsigned short*)outp;
        #pragma unroll
        for (int g = 0; g < 2; ++g) {
            int mb = m0 + g * 16;
            #pragma unroll
            for (int reg = 0; reg < 4; ++reg) {
                int row = mb + lhi * 4 + reg;
                float tv[8];
                float s = 0.f;
                #pragma unroll
                for (int t = 0; t < 8; ++t) {
                    tv[t] = (g ? acc1[t][reg] : acc0[t][reg]) + bcol[t];
                    s += tv[t];
                }
                #pragma unroll
                for (int msk = 1; msk < 16; msk <<= 1) s += __shfl_xor(s, msk);
                float mu = s * (1.0f / 128.0f);
                float q = 0.f;
                #pragma unroll
                for (int t = 0; t < 8; ++t) { float d = tv[t] - mu; q += d * d; }
                #pragma unroll
                for (int msk = 1; msk < 16; msk <<= 1) q += __shfl_xor(q, msk);
                float rs = rsqrtf(q * (1.0f / 128.0f) + 1e-5f);
                if (row < N) {
                    #pragma unroll
                    for (int t = 0; t < 8; ++t) {
                        float u = gelu_exact((tv[t] - mu) * rs * gcol[t] + lbcol[t]);
                        out[(size_t)row * 128 + t * 16 + l15] = f2bf(u);
                    }
                }
            }
        }
    } else {
        float* out = (float*)outp;
        #pragma unroll
        for (int g = 0; g < 2; ++g) {
            int mb = m0 + g * 16;
            #pragma unroll
            for (int reg = 0; reg < 4; ++reg) {
                int row = mb + lhi * 4 + reg;
                if (row < N) {
                    #pragma unroll
                    for (int t = 0; t < 8; ++t) {
                        size_t idx = (size_t)row * 128 + t * 16 + l15;
                        out[idx] = (g ? acc1[t][reg] : acc0[t][reg]) + bcol[t] + xres[idx];
                    }
                }
            }
        }
    }
}

extern "C" void kernel_launch(void* const* d_in, const int* in_sizes, int n_in,
                              void* d_out, int out_size, void* d_ws, size_t ws_size,
                              hipStream_t stream) {
    const float* x     = (const float*)d_in[0];
    const int*   ei    = (const int*)d_in[1];
    const float* attr  = (const float*)d_in[2];
    const float* ln1g  = (const float*)d_in[3];
    const float* ln1b  = (const float*)d_in[4];
    const float* W1    = (const float*)d_in[5];
    const float* root1 = (const float*)d_in[6];
    const float* b1    = (const float*)d_in[7];
    const float* ln2g  = (const float*)d_in[8];
    const float* ln2b  = (const float*)d_in[9];
    const float* W2    = (const float*)d_in[10];
    const float* root2 = (const float*)d_in[11];
    const float* b2    = (const float*)d_in[12];

    const int N = in_sizes[0] / 128;   // 50000
    const int E = in_sizes[1] / 2;     // 600000

    // workspace layout; y/z padded to 50048 rows (391 blocks x 128) for
    // OOB-safe A-frag reads in the last GEMM block
    char* ws = (char*)d_ws;
    unsigned short* y1    = (unsigned short*)(ws);                    // 12,812,288 (+pad)
    unsigned short* y2    = (unsigned short*)(ws + 12900000);         // 12,812,288 (+pad)
    unsigned short* z     = (unsigned short*)(ws + 25800000);         // 102,498,304 (+pad)
    unsigned short* Bf1   = (unsigned short*)(ws + 128400000);        // 294,912
    unsigned short* Bf2   = (unsigned short*)(ws + 128700000);        // 294,912
    int*            cnt   = (int*)(ws + 129000000);                   // 200,704
    int*            part  = (int*)(ws + 129210000);                   // 200,704
    int*            bsum  = (int*)(ws + 129420000);                   // 1,024
    int*            rowptr= (int*)(ws + 129430000);                   // 200,000
    int*            woff  = (int*)(ws + 129640000);                   // 200,000
    int*            esrc  = (int*)(ws + 129850000);                   // 2,400,000
    float4*         eattr = (float4*)(ws + 132250000);                // 19,200,000

    const int scanBlocks  = (N + 255) / 256;               // 196
    const int edgeBlocksE = (E + 255) / 256;               // 2344
    const int rowsBlocks  = (N * 64 + 255) / 256;          // 12500
    const int nodeBlocks  = (N + 3) / 4;                   // 12500
    const int gemmBlocks  = (N + 127) / 128;               // 391

    // weights -> fragment order (both layers, one launch)
    prep_w<<<1152, 256, 0, stream>>>(W1, root1, Bf1, W2, root2, Bf2);

    // CSR build (by dst)
    zero_i32<<<scanBlocks, 256, 0, stream>>>(cnt, scanBlocks * 256);
    hist_dst<<<edgeBlocksE, 256, 0, stream>>>(ei, cnt, E);
    scan1<<<scanBlocks, 256, 0, stream>>>(cnt, part, bsum, N);
    scan2<<<1, 256, 0, stream>>>(bsum, scanBlocks);
    scan3<<<scanBlocks, 256, 0, stream>>>(part, bsum, rowptr, woff, N);
    scatter_edges<<<edgeBlocksE, 256, 0, stream>>>(ei, (const float4*)attr, woff, esrc, eattr, E);

    // ---- layer 1 ----
    ln_gelu<<<rowsBlocks, 256, 0, stream>>>(x, ln1g, ln1b, y1, N);
    edge_z<<<nodeBlocks, 256, 0, stream>>>(rowptr, esrc, eattr, y1, z, N, E);
    gemm_fused<0><<<gemmBlocks, 256, 0, stream>>>(z, y1, Bf1, b1, ln2g, ln2b, nullptr, (void*)y2, N);

    // ---- layer 2 ----
    edge_z<<<nodeBlocks, 256, 0, stream>>>(rowptr, esrc, eattr, y2, z, N, E);
    gemm_fused<1><<<gemmBlocks, 256, 0, stream>>>(z, y2, Bf2, b2, nullptr, nullptr, x, d_out, N);
}

// Round 6
// 302.197 us; speedup vs baseline: 1.3797x; 1.0003x over previous
//
#include <hip/hip_runtime.h>
#include <hip/hip_bf16.h>

typedef __attribute__((ext_vector_type(8))) short short8;
typedef __attribute__((ext_vector_type(4))) float f32x4;

// A matrix layout: [50048][1152] bf16. Cols 0..1023 = z (k' = d*8+r order),
// cols 1024..1151 = y (LN+GELU activations). Row stride 1152 elems = 2304 B.
#define LDA 1152

__device__ __forceinline__ float bf2f(unsigned short u) {
    union { unsigned int i; float f; } v; v.i = ((unsigned int)u) << 16; return v.f;
}
__device__ __forceinline__ unsigned short f2bf(float f) {
    __hip_bfloat16 h = __float2bfloat16(f);
    union { __hip_bfloat16 h; unsigned short u; } v; v.h = h; return v.u;
}
__device__ __forceinline__ float gelu_exact(float t) {
    return 0.5f * t * (1.0f + erff(t * 0.70710678118654752f));
}

// ---------------------------------------------------------------------------
// Pack B = [W | root] (1152 x 128) into MFMA B-fragment order with K-axis
// permutation k' = d*8 + r (d = input dim, r = relation); k' = 1024 + d for root.
//   Bfrag[((kb*8 + t)*64 + lane)*8 + j] = B[k'][n]
//   kb = k'>>5, lane = ((k'>>3)&3)<<4 | (n&15), j = k'&7, t = n>>4
// Both layers in one launch.
// ---------------------------------------------------------------------------
__global__ void prep_w(const float* __restrict__ W1, const float* __restrict__ root1,
                       unsigned short* __restrict__ Bf1,
                       const float* __restrict__ W2, const float* __restrict__ root2,
                       unsigned short* __restrict__ Bf2) {
    int i = blockIdx.x * 256 + threadIdx.x;
    const float* W = W1; const float* root = root1; unsigned short* Bfrag = Bf1;
    if (i >= 1152 * 128) {
        i -= 1152 * 128; W = W2; root = root2; Bfrag = Bf2;
        if (i >= 1152 * 128) return;
    }
    int kp = i >> 7, n = i & 127;
    float v;
    if (kp < 1024) {
        int d = kp >> 3, r = kp & 7;
        v = W[((size_t)r * 128 + d) * 128 + n];
    } else {
        v = root[(size_t)(kp - 1024) * 128 + n];
    }
    int kb = kp >> 5;
    int lane = (((kp >> 3) & 3) << 4) | (n & 15);
    int j = kp & 7;
    int t = n >> 4;
    Bfrag[(((size_t)(kb * 8 + t) * 64 + lane) << 3) + j] = f2bf(v);
}

// ---------------------------------------------------------------------------
// CSR build
// ---------------------------------------------------------------------------
__global__ void zero_i32(int* __restrict__ p, int n) {
    int i = blockIdx.x * 256 + threadIdx.x;
    if (i < n) p[i] = 0;
}

__global__ void hist_dst(const int* __restrict__ ei, int* __restrict__ cnt, int E) {
    int e = blockIdx.x * 256 + threadIdx.x;
    if (e >= E) return;
    atomicAdd(&cnt[ei[E + e]], 1);
}

__global__ void scan1(const int* __restrict__ cnt, int* __restrict__ part,
                      int* __restrict__ bsum, int N) {
    int i = blockIdx.x * 256 + threadIdx.x;
    int v = (i < N) ? cnt[i] : 0;
    int lane = threadIdx.x & 63, wid = threadIdx.x >> 6;
    int s = v;
    #pragma unroll
    for (int off = 1; off < 64; off <<= 1) {
        int t = __shfl_up(s, off);
        if (lane >= off) s += t;
    }
    __shared__ int wsum[4];
    if (lane == 63) wsum[wid] = s;
    __syncthreads();
    int add = 0;
    for (int w = 0; w < wid; ++w) add += wsum[w];
    s += add;
    part[i] = s - v;
    if (threadIdx.x == 255) bsum[blockIdx.x] = s;
}

__global__ void scan2(int* __restrict__ bsum, int nb) {
    int i = threadIdx.x;
    int v = (i < nb) ? bsum[i] : 0;
    int lane = threadIdx.x & 63, wid = threadIdx.x >> 6;
    int s = v;
    #pragma unroll
    for (int off = 1; off < 64; off <<= 1) {
        int t = __shfl_up(s, off);
        if (lane >= off) s += t;
    }
    __shared__ int wsum[4];
    if (lane == 63) wsum[wid] = s;
    __syncthreads();
    int add = 0;
    for (int w = 0; w < wid; ++w) add += wsum[w];
    s += add;
    if (i < nb) bsum[i] = s - v;
}

__global__ void scan3(const int* __restrict__ part, const int* __restrict__ bsum,
                      int* __restrict__ rowptr, int* __restrict__ woff, int N) {
    int i = blockIdx.x * 256 + threadIdx.x;
    if (i >= N) return;
    int v = part[i] + bsum[blockIdx.x];
    rowptr[i] = v;
    woff[i] = v;
}

__global__ void scatter_edges(const int* __restrict__ ei, const float4* __restrict__ attr,
                              int* __restrict__ woff, int* __restrict__ esrc,
                              float4* __restrict__ eattr, int E) {
    int e = blockIdx.x * 256 + threadIdx.x;
    if (e >= E) return;
    int src = ei[e], dst = ei[E + e];
    int p = atomicAdd(&woff[dst], 1);
    esrc[p] = src;
    eattr[2 * p]     = attr[2 * e];
    eattr[2 * p + 1] = attr[2 * e + 1];
}

// ---------------------------------------------------------------------------
// LN + GELU on x (fp32 in) -> A tail cols 1024..1151 (bf16). One wave per row.
// ---------------------------------------------------------------------------
__global__ void ln_gelu(const float* __restrict__ x, const float* __restrict__ g,
                        const float* __restrict__ b, unsigned short* __restrict__ A, int N) {
    int row = (blockIdx.x * blockDim.x + threadIdx.x) >> 6;
    if (row >= N) return;
    int lane = threadIdx.x & 63;
    float2 v = *(const float2*)(x + (size_t)row * 128 + lane * 2);
    float s = v.x + v.y;
    #pragma unroll
    for (int o = 32; o; o >>= 1) s += __shfl_xor(s, o);
    float mu = s * (1.0f / 128.0f);
    float d0 = v.x - mu, d1 = v.y - mu;
    float q = d0 * d0 + d1 * d1;
    #pragma unroll
    for (int o = 32; o; o >>= 1) q += __shfl_xor(q, o);
    float rs = rsqrtf(q * (1.0f / 128.0f) + 1e-5f);
    float2 gg = *(const float2*)(g + lane * 2);
    float2 bb = *(const float2*)(b + lane * 2);
    ushort2 o2;
    o2.x = f2bf(gelu_exact(d0 * rs * gg.x + bb.x));
    o2.y = f2bf(gelu_exact(d1 * rs * gg.y + bb.y));
    *(ushort2*)(A + (size_t)row * LDA + 1024 + lane * 2) = o2;
}

// ---------------------------------------------------------------------------
// Edge aggregation into A cols 0..1023 (k'-ordered). One wave per dst node;
// gathers y from A tail (cols 1024..1151). Unrolled x8 -> 8 gathers in flight.
// ---------------------------------------------------------------------------
__global__ __launch_bounds__(256) void edge_z(const int* __restrict__ rowptr,
                                              const int* __restrict__ esrc,
                                              const float4* __restrict__ eattr,
                                              unsigned short* __restrict__ A, int N, int E) {
    int row = (blockIdx.x << 2) + (threadIdx.x >> 6);
    if (row >= N) return;
    int lane = threadIdx.x & 63;
    int e0 = rowptr[row];
    int e1 = (row + 1 < N) ? rowptr[row + 1] : E;
    float a0[8] = {0,0,0,0,0,0,0,0};
    float a1[8] = {0,0,0,0,0,0,0,0};
    const unsigned short* yl = A + 1024 + lane * 2;

    #define EDGE_FMA(hv, W0, W1) do {                                  \
        float y0 = bf2f((unsigned short)((hv) & 0xffffu));             \
        float y1 = bf2f((unsigned short)((hv) >> 16));                 \
        a0[0] += (W0).x * y0; a1[0] += (W0).x * y1;                    \
        a0[1] += (W0).y * y0; a1[1] += (W0).y * y1;                    \
        a0[2] += (W0).z * y0; a1[2] += (W0).z * y1;                    \
        a0[3] += (W0).w * y0; a1[3] += (W0).w * y1;                    \
        a0[4] += (W1).x * y0; a1[4] += (W1).x * y1;                    \
        a0[5] += (W1).y * y0; a1[5] += (W1).y * y1;                    \
        a0[6] += (W1).z * y0; a1[6] += (W1).z * y1;                    \
        a0[7] += (W1).w * y0; a1[7] += (W1).w * y1;                    \
    } while (0)

    int e = e0;
    for (; e + 8 <= e1; e += 8) {
        unsigned int h[8];
        #pragma unroll
        for (int u = 0; u < 8; ++u)
            h[u] = *(const unsigned int*)(yl + (size_t)esrc[e + u] * LDA);
        #pragma unroll
        for (int u = 0; u < 8; ++u) {
            float4 w0 = eattr[2 * (e + u)], w1 = eattr[2 * (e + u) + 1];
            EDGE_FMA(h[u], w0, w1);
        }
    }
    for (; e + 4 <= e1; e += 4) {
        unsigned int h[4];
        #pragma unroll
        for (int u = 0; u < 4; ++u)
            h[u] = *(const unsigned int*)(yl + (size_t)esrc[e + u] * LDA);
        #pragma unroll
        for (int u = 0; u < 4; ++u) {
            float4 w0 = eattr[2 * (e + u)], w1 = eattr[2 * (e + u) + 1];
            EDGE_FMA(h[u], w0, w1);
        }
    }
    for (; e < e1; ++e) {
        unsigned int h = *(const unsigned int*)(yl + (size_t)esrc[e] * LDA);
        float4 w0 = eattr[2 * e], w1 = eattr[2 * e + 1];
        EDGE_FMA(h, w0, w1);
    }
    #undef EDGE_FMA

    short8 p0, p1;
    #pragma unroll
    for (int r = 0; r < 8; ++r) { p0[r] = (short)f2bf(a0[r]); p1[r] = (short)f2bf(a1[r]); }
    unsigned short* zr = A + (size_t)row * LDA + lane * 16;
    *(short8*)zr = p0;
    *(short8*)(zr + 8) = p1;
}

// ---------------------------------------------------------------------------
// GEMM v3: A (N x 1152 bf16) @ B (1152 x 128) — barrier-free, LDS-free.
// Wave = 32 rows x 128 cols; B-fragments double-buffered in REGISTERS
// (coalesced 1KB/instr loads, L2-resident broadcast). A double-buffered too.
// Compiler inserts counted s_waitcnt; no __syncthreads anywhere.
// MODE 0: gelu(LN(C+bias)) -> bf16 into A tail (own rows: read-before-write safe).
// MODE 1: C+bias+xres -> fp32 out [N][128].
// ---------------------------------------------------------------------------
template <int MODE>
__global__ __launch_bounds__(256) void gemm_fused(
        unsigned short* __restrict__ A, const unsigned short* __restrict__ Bfrag,
        const float* __restrict__ bias, const float* __restrict__ lng,
        const float* __restrict__ lnb, const float* __restrict__ xres,
        float* __restrict__ outp, int N) {
    int gw = (blockIdx.x * 256 + threadIdx.x) >> 6;
    int lane = threadIdx.x & 63;
    int l15 = lane & 15, lhi = lane >> 4;
    int m0 = gw * 32;

    const unsigned short* a0p = A + (size_t)(m0 + l15) * LDA + lhi * 8;
    const unsigned short* a1p = a0p + 16 * LDA;
    const short8* bfb = (const short8*)Bfrag + lane;

    short8 bA[8], bB[8];
    #pragma unroll
    for (int t = 0; t < 8; ++t) bA[t] = bfb[t * 64];
    short8 aA0 = *(const short8*)a0p;
    short8 aA1 = *(const short8*)a1p;

    f32x4 acc0[8] = {}, acc1[8] = {};
    for (int kb = 0; kb < 36; kb += 2) {
        // prefetch kb+1 (always exists: 36 even)
        #pragma unroll
        for (int t = 0; t < 8; ++t) bB[t] = bfb[((kb + 1) * 8 + t) * 64];
        short8 aB0 = *(const short8*)(a0p + (kb + 1) * 32);
        short8 aB1 = *(const short8*)(a1p + (kb + 1) * 32);
        #pragma unroll
        for (int t = 0; t < 8; ++t) {
            acc0[t] = __builtin_amdgcn_mfma_f32_16x16x32_bf16(aA0, bA[t], acc0[t], 0, 0, 0);
            acc1[t] = __builtin_amdgcn_mfma_f32_16x16x32_bf16(aA1, bA[t], acc1[t], 0, 0, 0);
        }
        if (kb + 2 < 36) {
            #pragma unroll
            for (int t = 0; t < 8; ++t) bA[t] = bfb[((kb + 2) * 8 + t) * 64];
            aA0 = *(const short8*)(a0p + (kb + 2) * 32);
            aA1 = *(const short8*)(a1p + (kb + 2) * 32);
        }
        #pragma unroll
        for (int t = 0; t < 8; ++t) {
            acc0[t] = __builtin_amdgcn_mfma_f32_16x16x32_bf16(aB0, bB[t], acc0[t], 0, 0, 0);
            acc1[t] = __builtin_amdgcn_mfma_f32_16x16x32_bf16(aB1, bB[t], acc1[t], 0, 0, 0);
        }
    }

    float bcol[8];
    #pragma unroll
    for (int t = 0; t < 8; ++t) bcol[t] = bias[t * 16 + l15];

    if (MODE == 0) {
        float gcol[8], lbcol[8];
        #pragma unroll
        for (int t = 0; t < 8; ++t) { gcol[t] = lng[t * 16 + l15]; lbcol[t] = lnb[t * 16 + l15]; }
        #pragma unroll
        for (int g = 0; g < 2; ++g) {
            int mb = m0 + g * 16;
            #pragma unroll
            for (int reg = 0; reg < 4; ++reg) {
                int row = mb + lhi * 4 + reg;
                float tv[8];
                float s = 0.f;
                #pragma unroll
                for (int t = 0; t < 8; ++t) {
                    tv[t] = (g ? acc1[t][reg] : acc0[t][reg]) + bcol[t];
                    s += tv[t];
                }
                #pragma unroll
                for (int msk = 1; msk < 16; msk <<= 1) s += __shfl_xor(s, msk);
                float mu = s * (1.0f / 128.0f);
                float q = 0.f;
                #pragma unroll
                for (int t = 0; t < 8; ++t) { float d = tv[t] - mu; q += d * d; }
                #pragma unroll
                for (int msk = 1; msk < 16; msk <<= 1) q += __shfl_xor(q, msk);
                float rs = rsqrtf(q * (1.0f / 128.0f) + 1e-5f);
                if (row < N) {
                    #pragma unroll
                    for (int t = 0; t < 8; ++t) {
                        float u = gelu_exact((tv[t] - mu) * rs * gcol[t] + lbcol[t]);
                        A[(size_t)row * LDA + 1024 + t * 16 + l15] = f2bf(u);
                    }
                }
            }
        }
    } else {
        #pragma unroll
        for (int g = 0; g < 2; ++g) {
            int mb = m0 + g * 16;
            #pragma unroll
            for (int reg = 0; reg < 4; ++reg) {
                int row = mb + lhi * 4 + reg;
                if (row < N) {
                    #pragma unroll
                    for (int t = 0; t < 8; ++t) {
                        size_t idx = (size_t)row * 128 + t * 16 + l15;
                        outp[idx] = (g ? acc1[t][reg] : acc0[t][reg]) + bcol[t] + xres[idx];
                    }
                }
            }
        }
    }
}

extern "C" void kernel_launch(void* const* d_in, const int* in_sizes, int n_in,
                              void* d_out, int out_size, void* d_ws, size_t ws_size,
                              hipStream_t stream) {
    const float* x     = (const float*)d_in[0];
    const int*   ei    = (const int*)d_in[1];
    const float* attr  = (const float*)d_in[2];
    const float* ln1g  = (const float*)d_in[3];
    const float* ln1b  = (const float*)d_in[4];
    const float* W1    = (const float*)d_in[5];
    const float* root1 = (const float*)d_in[6];
    const float* b1    = (const float*)d_in[7];
    const float* ln2g  = (const float*)d_in[8];
    const float* ln2b  = (const float*)d_in[9];
    const float* W2    = (const float*)d_in[10];
    const float* root2 = (const float*)d_in[11];
    const float* b2    = (const float*)d_in[12];

    const int N = in_sizes[0] / 128;   // 50000
    const int E = in_sizes[1] / 2;     // 600000

    // workspace layout; A padded to 50048 rows (1564 waves x 32) for OOB-safe
    // A-frag reads in the last GEMM block.
    char* ws = (char*)d_ws;
    unsigned short* A     = (unsigned short*)(ws);                    // 115,310,592
    unsigned short* Bf1   = (unsigned short*)(ws + 115400000);        // 294,912
    unsigned short* Bf2   = (unsigned short*)(ws + 115700000);        // 294,912
    int*            cnt   = (int*)(ws + 116000000);                   // 200,704
    int*            part  = (int*)(ws + 116210000);                   // 200,704
    int*            bsum  = (int*)(ws + 116420000);                   // 1,024
    int*            rowptr= (int*)(ws + 116430000);                   // 200,000
    int*            woff  = (int*)(ws + 116640000);                   // 200,000
    int*            esrc  = (int*)(ws + 116850000);                   // 2,400,000
    float4*         eattr = (float4*)(ws + 119250000);                // 19,200,000

    const int scanBlocks  = (N + 255) / 256;               // 196
    const int edgeBlocksE = (E + 255) / 256;               // 2344
    const int rowsBlocks  = (N * 64 + 255) / 256;          // 12500
    const int nodeBlocks  = (N + 3) / 4;                   // 12500
    const int gemmBlocks  = (N + 127) / 128;               // 391

    // weights -> fragment order (both layers, one launch)
    prep_w<<<1152, 256, 0, stream>>>(W1, root1, Bf1, W2, root2, Bf2);

    // CSR build (by dst)
    zero_i32<<<scanBlocks, 256, 0, stream>>>(cnt, scanBlocks * 256);
    hist_dst<<<edgeBlocksE, 256, 0, stream>>>(ei, cnt, E);
    scan1<<<scanBlocks, 256, 0, stream>>>(cnt, part, bsum, N);
    scan2<<<1, 256, 0, stream>>>(bsum, scanBlocks);
    scan3<<<scanBlocks, 256, 0, stream>>>(part, bsum, rowptr, woff, N);
    scatter_edges<<<edgeBlocksE, 256, 0, stream>>>(ei, (const float4*)attr, woff, esrc, eattr, E);

    // ---- layer 1 ----
    ln_gelu<<<rowsBlocks, 256, 0, stream>>>(x, ln1g, ln1b, A, N);
    edge_z<<<nodeBlocks, 256, 0, stream>>>(rowptr, esrc, eattr, A, N, E);
    gemm_fused<0><<<gemmBlocks, 256, 0, stream>>>(A, Bf1, b1, ln2g, ln2b, nullptr, nullptr, N);

    // ---- layer 2 ----
    edge_z<<<nodeBlocks, 256, 0, stream>>>(rowptr, esrc, eattr, A, N, E);
    gemm_fused<1><<<gemmBlocks, 256, 0, stream>>>(A, Bf2, b2, nullptr, nullptr, x, (float*)d_out, N);
}

// Round 7
// 258.227 us; speedup vs baseline: 1.6146x; 1.1703x over previous
//
#include <hip/hip_runtime.h>
#include <hip/hip_bf16.h>

typedef __attribute__((ext_vector_type(8))) short short8;
typedef __attribute__((ext_vector_type(4))) float f32x4;

// A matrix layout: [50176][1152] bf16. Cols 0..1023 = z (k' = d*8+r order),
// cols 1024..1151 = y (LN+GELU activations). Row stride 1152 elems = 2304 B.
#define LDA 1152

__device__ __forceinline__ float bf2f(unsigned short u) {
    union { unsigned int i; float f; } v; v.i = ((unsigned int)u) << 16; return v.f;
}
__device__ __forceinline__ unsigned short f2bf(float f) {
    __hip_bfloat16 h = __float2bfloat16(f);
    union { __hip_bfloat16 h; unsigned short u; } v; v.h = h; return v.u;
}
__device__ __forceinline__ float gelu_exact(float t) {
    return 0.5f * t * (1.0f + erff(t * 0.70710678118654752f));
}

// ---------------------------------------------------------------------------
// Pack B = [W | root] (1152 x 128) into MFMA B-fragment order with K-axis
// permutation k' = d*8 + r (d = input dim, r = relation); k' = 1024 + d for root.
//   Bfrag[((kb*8 + t)*64 + lane)*8 + j] = B[k'][n]
//   kb = k'>>5, lane = ((k'>>3)&3)<<4 | (n&15), j = k'&7, t = n>>4
// Both layers in one launch.
// ---------------------------------------------------------------------------
__global__ void prep_w(const float* __restrict__ W1, const float* __restrict__ root1,
                       unsigned short* __restrict__ Bf1,
                       const float* __restrict__ W2, const float* __restrict__ root2,
                       unsigned short* __restrict__ Bf2) {
    int i = blockIdx.x * 256 + threadIdx.x;
    const float* W = W1; const float* root = root1; unsigned short* Bfrag = Bf1;
    if (i >= 1152 * 128) {
        i -= 1152 * 128; W = W2; root = root2; Bfrag = Bf2;
        if (i >= 1152 * 128) return;
    }
    int kp = i >> 7, n = i & 127;
    float v;
    if (kp < 1024) {
        int d = kp >> 3, r = kp & 7;
        v = W[((size_t)r * 128 + d) * 128 + n];
    } else {
        v = root[(size_t)(kp - 1024) * 128 + n];
    }
    int kb = kp >> 5;
    int lane = (((kp >> 3) & 3) << 4) | (n & 15);
    int j = kp & 7;
    int t = n >> 4;
    Bfrag[(((size_t)(kb * 8 + t) * 64 + lane) << 3) + j] = f2bf(v);
}

// ---------------------------------------------------------------------------
// CSR build
// ---------------------------------------------------------------------------
__global__ void zero_i32(int* __restrict__ p, int n) {
    int i = blockIdx.x * 256 + threadIdx.x;
    if (i < n) p[i] = 0;
}

__global__ void hist_dst(const int* __restrict__ ei, int* __restrict__ cnt, int E) {
    int e = blockIdx.x * 256 + threadIdx.x;
    if (e >= E) return;
    atomicAdd(&cnt[ei[E + e]], 1);
}

__global__ void scan1(const int* __restrict__ cnt, int* __restrict__ part,
                      int* __restrict__ bsum, int N) {
    int i = blockIdx.x * 256 + threadIdx.x;
    int v = (i < N) ? cnt[i] : 0;
    int lane = threadIdx.x & 63, wid = threadIdx.x >> 6;
    int s = v;
    #pragma unroll
    for (int off = 1; off < 64; off <<= 1) {
        int t = __shfl_up(s, off);
        if (lane >= off) s += t;
    }
    __shared__ int wsum[4];
    if (lane == 63) wsum[wid] = s;
    __syncthreads();
    int add = 0;
    for (int w = 0; w < wid; ++w) add += wsum[w];
    s += add;
    part[i] = s - v;
    if (threadIdx.x == 255) bsum[blockIdx.x] = s;
}

__global__ void scan2(int* __restrict__ bsum, int nb) {
    int i = threadIdx.x;
    int v = (i < nb) ? bsum[i] : 0;
    int lane = threadIdx.x & 63, wid = threadIdx.x >> 6;
    int s = v;
    #pragma unroll
    for (int off = 1; off < 64; off <<= 1) {
        int t = __shfl_up(s, off);
        if (lane >= off) s += t;
    }
    __shared__ int wsum[4];
    if (lane == 63) wsum[wid] = s;
    __syncthreads();
    int add = 0;
    for (int w = 0; w < wid; ++w) add += wsum[w];
    s += add;
    if (i < nb) bsum[i] = s - v;
}

__global__ void scan3(const int* __restrict__ part, const int* __restrict__ bsum,
                      int* __restrict__ rowptr, int* __restrict__ woff, int N) {
    int i = blockIdx.x * 256 + threadIdx.x;
    if (i >= N) return;
    int v = part[i] + bsum[blockIdx.x];
    rowptr[i] = v;
    woff[i] = v;
}

// eattr stored bf16-packed: 8 relations -> 16B per edge
__global__ void scatter_edges(const int* __restrict__ ei, const float4* __restrict__ attr,
                              int* __restrict__ woff, int* __restrict__ esrc,
                              short8* __restrict__ eattr, int E) {
    int e = blockIdx.x * 256 + threadIdx.x;
    if (e >= E) return;
    int src = ei[e], dst = ei[E + e];
    float4 a0 = attr[2 * e], a1 = attr[2 * e + 1];
    short8 pk;
    pk[0] = (short)f2bf(a0.x); pk[1] = (short)f2bf(a0.y);
    pk[2] = (short)f2bf(a0.z); pk[3] = (short)f2bf(a0.w);
    pk[4] = (short)f2bf(a1.x); pk[5] = (short)f2bf(a1.y);
    pk[6] = (short)f2bf(a1.z); pk[7] = (short)f2bf(a1.w);
    int p = atomicAdd(&woff[dst], 1);
    esrc[p] = src;
    eattr[p] = pk;
}

// ---------------------------------------------------------------------------
// LN + GELU on x (fp32 in) -> A tail cols 1024..1151 (bf16). One wave per row.
// ---------------------------------------------------------------------------
__global__ void ln_gelu(const float* __restrict__ x, const float* __restrict__ g,
                        const float* __restrict__ b, unsigned short* __restrict__ A, int N) {
    int row = (blockIdx.x * blockDim.x + threadIdx.x) >> 6;
    if (row >= N) return;
    int lane = threadIdx.x & 63;
    float2 v = *(const float2*)(x + (size_t)row * 128 + lane * 2);
    float s = v.x + v.y;
    #pragma unroll
    for (int o = 32; o; o >>= 1) s += __shfl_xor(s, o);
    float mu = s * (1.0f / 128.0f);
    float d0 = v.x - mu, d1 = v.y - mu;
    float q = d0 * d0 + d1 * d1;
    #pragma unroll
    for (int o = 32; o; o >>= 1) q += __shfl_xor(q, o);
    float rs = rsqrtf(q * (1.0f / 128.0f) + 1e-5f);
    float2 gg = *(const float2*)(g + lane * 2);
    float2 bb = *(const float2*)(b + lane * 2);
    ushort2 o2;
    o2.x = f2bf(gelu_exact(d0 * rs * gg.x + bb.x));
    o2.y = f2bf(gelu_exact(d1 * rs * gg.y + bb.y));
    *(ushort2*)(A + (size_t)row * LDA + 1024 + lane * 2) = o2;
}

// ---------------------------------------------------------------------------
// Edge aggregation into A cols 0..1023 (k'-ordered). One wave per dst node;
// gathers y from A tail. Unrolled x4 (4 gathers in flight). bf16 eattr.
// ---------------------------------------------------------------------------
__global__ __launch_bounds__(256) void edge_z(const int* __restrict__ rowptr,
                                              const int* __restrict__ esrc,
                                              const short8* __restrict__ eattr,
                                              unsigned short* __restrict__ A, int N, int E) {
    int row = (blockIdx.x << 2) + (threadIdx.x >> 6);
    if (row >= N) return;
    int lane = threadIdx.x & 63;
    int e0 = rowptr[row];
    int e1 = (row + 1 < N) ? rowptr[row + 1] : E;
    float a0[8] = {0,0,0,0,0,0,0,0};
    float a1[8] = {0,0,0,0,0,0,0,0};
    const unsigned short* yl = A + 1024 + lane * 2;

    #define EDGE_FMA(hv, ea) do {                                      \
        float y0 = bf2f((unsigned short)((hv) & 0xffffu));             \
        float y1 = bf2f((unsigned short)((hv) >> 16));                 \
        _Pragma("unroll")                                              \
        for (int r = 0; r < 8; ++r) {                                  \
            float wv = bf2f((unsigned short)(ea)[r]);                  \
            a0[r] += wv * y0; a1[r] += wv * y1;                        \
        }                                                              \
    } while (0)

    int e = e0;
    for (; e + 4 <= e1; e += 4) {
        unsigned int h[4];
        short8 ea[4];
        #pragma unroll
        for (int u = 0; u < 4; ++u) {
            h[u] = *(const unsigned int*)(yl + (size_t)esrc[e + u] * LDA);
            ea[u] = eattr[e + u];
        }
        #pragma unroll
        for (int u = 0; u < 4; ++u) EDGE_FMA(h[u], ea[u]);
    }
    for (; e < e1; ++e) {
        unsigned int h = *(const unsigned int*)(yl + (size_t)esrc[e] * LDA);
        short8 ea = eattr[e];
        EDGE_FMA(h, ea);
    }
    #undef EDGE_FMA

    short8 p0, p1;
    #pragma unroll
    for (int r = 0; r < 8; ++r) { p0[r] = (short)f2bf(a0[r]); p1[r] = (short)f2bf(a1[r]); }
    unsigned short* zr = A + (size_t)row * LDA + lane * 16;
    *(short8*)zr = p0;
    *(short8*)(zr + 8) = p1;
}

// ---------------------------------------------------------------------------
// GEMM v4: A (N x 1152 bf16) @ B (1152 x 128).
// Block = 512 threads (8 waves) = 256 rows; wave = 32 rows x 128 cols.
// B staged in 32KB chunks (4 kb-steps) in double-buffered LDS via
// global_load_lds -> 9 barriers total, 64 MFMA between barrier pairs, and
// each block reads B exactly once (56 MB aggregate vs 450 MB in v3).
// A-frag loads for chunk c+1 issued after chunk-c MFMAs, before the barrier
// (they drain with the barrier's vmcnt(0) and are ready next chunk).
// MODE 0: gelu(LN(C+bias)) -> bf16 into A tail (own rows only).
// MODE 1: C+bias+xres -> fp32 out [N][128].
// ---------------------------------------------------------------------------
template <int MODE>
__global__ __launch_bounds__(512) void gemm_fused(
        unsigned short* __restrict__ A, const unsigned short* __restrict__ Bfrag,
        const float* __restrict__ bias, const float* __restrict__ lng,
        const float* __restrict__ lnb, const float* __restrict__ xres,
        float* __restrict__ outp, int N) {
    __shared__ short8 Bs[2][2048];   // 2 x 32 KB

    int w = threadIdx.x >> 6;        // 0..7
    int lane = threadIdx.x & 63;
    int l15 = lane & 15, lhi = lane >> 4;
    int m0 = blockIdx.x * 256 + w * 32;

    const unsigned short* a0p = A + (size_t)(m0 + l15) * LDA + lhi * 8;
    const unsigned short* a1p = a0p + 16 * LDA;
    const short8* bfb = (const short8*)Bfrag;

    // stage chunk c (kb = 4c..4c+3) = 2048 short8 = 32KB; 4 gload_lds per thread
    #define STAGE(buf, c)                                                          \
        do {                                                                       \
            const short8* gsrc = bfb + (size_t)(c) * 2048 + w * 64;                \
            _Pragma("unroll")                                                      \
            for (int i = 0; i < 4; ++i)                                            \
                __builtin_amdgcn_global_load_lds(&gsrc[i * 512 + lane],            \
                                                 &Bs[buf][w * 64 + i * 512], 16, 0, 0); \
        } while (0)

    STAGE(0, 0);
    short8 af0[4], af1[4];
    #pragma unroll
    for (int k = 0; k < 4; ++k) {
        af0[k] = *(const short8*)(a0p + k * 32);
        af1[k] = *(const short8*)(a1p + k * 32);
    }
    __syncthreads();

    f32x4 acc0[8] = {}, acc1[8] = {};
    for (int c = 0; c < 9; ++c) {
        int cur = c & 1;
        if (c < 8) STAGE(cur ^ 1, c + 1);
        #pragma unroll
        for (int k = 0; k < 4; ++k) {
            #pragma unroll
            for (int t = 0; t < 8; ++t) {
                short8 b = Bs[cur][k * 512 + t * 64 + lane];
                acc0[t] = __builtin_amdgcn_mfma_f32_16x16x32_bf16(af0[k], b, acc0[t], 0, 0, 0);
                acc1[t] = __builtin_amdgcn_mfma_f32_16x16x32_bf16(af1[k], b, acc1[t], 0, 0, 0);
            }
        }
        if (c < 8) {
            #pragma unroll
            for (int k = 0; k < 4; ++k) {
                af0[k] = *(const short8*)(a0p + ((c + 1) * 4 + k) * 32);
                af1[k] = *(const short8*)(a1p + ((c + 1) * 4 + k) * 32);
            }
            __syncthreads();
        }
    }
    #undef STAGE

    float bcol[8];
    #pragma unroll
    for (int t = 0; t < 8; ++t) bcol[t] = bias[t * 16 + l15];

    if (MODE == 0) {
        float gcol[8], lbcol[8];
        #pragma unroll
        for (int t = 0; t < 8; ++t) { gcol[t] = lng[t * 16 + l15]; lbcol[t] = lnb[t * 16 + l15]; }
        #pragma unroll
        for (int g = 0; g < 2; ++g) {
            int mb = m0 + g * 16;
            #pragma unroll
            for (int reg = 0; reg < 4; ++reg) {
                int row = mb + lhi * 4 + reg;
                float tv[8];
                float s = 0.f;
                #pragma unroll
                for (int t = 0; t < 8; ++t) {
                    tv[t] = (g ? acc1[t][reg] : acc0[t][reg]) + bcol[t];
                    s += tv[t];
                }
                #pragma unroll
                for (int msk = 1; msk < 16; msk <<= 1) s += __shfl_xor(s, msk);
                float mu = s * (1.0f / 128.0f);
                float q = 0.f;
                #pragma unroll
                for (int t = 0; t < 8; ++t) { float d = tv[t] - mu; q += d * d; }
                #pragma unroll
                for (int msk = 1; msk < 16; msk <<= 1) q += __shfl_xor(q, msk);
                float rs = rsqrtf(q * (1.0f / 128.0f) + 1e-5f);
                if (row < N) {
                    #pragma unroll
                    for (int t = 0; t < 8; ++t) {
                        float u = gelu_exact((tv[t] - mu) * rs * gcol[t] + lbcol[t]);
                        A[(size_t)row * LDA + 1024 + t * 16 + l15] = f2bf(u);
                    }
                }
            }
        }
    } else {
        #pragma unroll
        for (int g = 0; g < 2; ++g) {
            int mb = m0 + g * 16;
            #pragma unroll
            for (int reg = 0; reg < 4; ++reg) {
                int row = mb + lhi * 4 + reg;
                if (row < N) {
                    #pragma unroll
                    for (int t = 0; t < 8; ++t) {
                        size_t idx = (size_t)row * 128 + t * 16 + l15;
                        outp[idx] = (g ? acc1[t][reg] : acc0[t][reg]) + bcol[t] + xres[idx];
                    }
                }
            }
        }
    }
}

extern "C" void kernel_launch(void* const* d_in, const int* in_sizes, int n_in,
                              void* d_out, int out_size, void* d_ws, size_t ws_size,
                              hipStream_t stream) {
    const float* x     = (const float*)d_in[0];
    const int*   ei    = (const int*)d_in[1];
    const float* attr  = (const float*)d_in[2];
    const float* ln1g  = (const float*)d_in[3];
    const float* ln1b  = (const float*)d_in[4];
    const float* W1    = (const float*)d_in[5];
    const float* root1 = (const float*)d_in[6];
    const float* b1    = (const float*)d_in[7];
    const float* ln2g  = (const float*)d_in[8];
    const float* ln2b  = (const float*)d_in[9];
    const float* W2    = (const float*)d_in[10];
    const float* root2 = (const float*)d_in[11];
    const float* b2    = (const float*)d_in[12];

    const int N = in_sizes[0] / 128;   // 50000
    const int E = in_sizes[1] / 2;     // 600000

    // workspace layout; A padded to 50176 rows (196 blocks x 256) for OOB-safe
    // A-frag reads in the last GEMM block. 50176*1152*2 = 115,605,504 B.
    char* ws = (char*)d_ws;
    unsigned short* A     = (unsigned short*)(ws);                    // 115,605,504
    unsigned short* Bf1   = (unsigned short*)(ws + 115700000);        // 294,912
    unsigned short* Bf2   = (unsigned short*)(ws + 116000000);        // 294,912
    int*            cnt   = (int*)(ws + 116300000);                   // 200,704
    int*            part  = (int*)(ws + 116510000);                   // 200,704
    int*            bsum  = (int*)(ws + 116720000);                   // 1,024
    int*            rowptr= (int*)(ws + 116730000);                   // 200,000
    int*            woff  = (int*)(ws + 116940000);                   // 200,000
    int*            esrc  = (int*)(ws + 117150000);                   // 2,400,000
    short8*         eattr = (short8*)(ws + 119560000);                // 9,600,000

    const int scanBlocks  = (N + 255) / 256;               // 196
    const int edgeBlocksE = (E + 255) / 256;               // 2344
    const int rowsBlocks  = (N * 64 + 255) / 256;          // 12500
    const int nodeBlocks  = (N + 3) / 4;                   // 12500
    const int gemmBlocks  = (N + 255) / 256;               // 196

    // weights -> fragment order (both layers, one launch)
    prep_w<<<1152, 256, 0, stream>>>(W1, root1, Bf1, W2, root2, Bf2);

    // CSR build (by dst)
    zero_i32<<<scanBlocks, 256, 0, stream>>>(cnt, scanBlocks * 256);
    hist_dst<<<edgeBlocksE, 256, 0, stream>>>(ei, cnt, E);
    scan1<<<scanBlocks, 256, 0, stream>>>(cnt, part, bsum, N);
    scan2<<<1, 256, 0, stream>>>(bsum, scanBlocks);
    scan3<<<scanBlocks, 256, 0, stream>>>(part, bsum, rowptr, woff, N);
    scatter_edges<<<edgeBlocksE, 256, 0, stream>>>(ei, (const float4*)attr, woff, esrc, eattr, E);

    // ---- layer 1 ----
    ln_gelu<<<rowsBlocks, 256, 0, stream>>>(x, ln1g, ln1b, A, N);
    edge_z<<<nodeBlocks, 256, 0, stream>>>(rowptr, esrc, eattr, A, N, E);
    gemm_fused<0><<<gemmBlocks, 512, 0, stream>>>(A, Bf1, b1, ln2g, ln2b, nullptr, nullptr, N);

    // ---- layer 2 ----
    edge_z<<<nodeBlocks, 256, 0, stream>>>(rowptr, esrc, eattr, A, N, E);
    gemm_fused<1><<<gemmBlocks, 512, 0, stream>>>(A, Bf2, b2, nullptr, nullptr, x, (float*)d_out, N);
}

// Round 8
// 253.967 us; speedup vs baseline: 1.6417x; 1.0168x over previous
//
#include <hip/hip_runtime.h>
#include <hip/hip_bf16.h>

typedef __attribute__((ext_vector_type(8))) short short8;
typedef __attribute__((ext_vector_type(4))) float f32x4;

// A matrix layout: [50048][1152] bf16. Cols 0..1023 = z (k' = d*8+r order),
// cols 1024..1151 = y (LN+GELU activations). Row stride 1152 elems = 2304 B.
#define LDA 1152

__device__ __forceinline__ float bf2f(unsigned short u) {
    union { unsigned int i; float f; } v; v.i = ((unsigned int)u) << 16; return v.f;
}
__device__ __forceinline__ unsigned short f2bf(float f) {
    __hip_bfloat16 h = __float2bfloat16(f);
    union { __hip_bfloat16 h; unsigned short u; } v; v.h = h; return v.u;
}
__device__ __forceinline__ float gelu_exact(float t) {
    return 0.5f * t * (1.0f + erff(t * 0.70710678118654752f));
}

// ---------------------------------------------------------------------------
// Pack B = [W | root] (1152 x 128) into MFMA B-fragment order with K-axis
// permutation k' = d*8 + r (d = input dim, r = relation); k' = 1024 + d for root.
//   Bfrag[((kb*8 + t)*64 + lane)*8 + j] = B[k'][n]
//   kb = k'>>5, lane = ((k'>>3)&3)<<4 | (n&15), j = k'&7, t = n>>4
// Both layers in one launch.
// ---------------------------------------------------------------------------
__global__ void prep_w(const float* __restrict__ W1, const float* __restrict__ root1,
                       unsigned short* __restrict__ Bf1,
                       const float* __restrict__ W2, const float* __restrict__ root2,
                       unsigned short* __restrict__ Bf2) {
    int i = blockIdx.x * 256 + threadIdx.x;
    const float* W = W1; const float* root = root1; unsigned short* Bfrag = Bf1;
    if (i >= 1152 * 128) {
        i -= 1152 * 128; W = W2; root = root2; Bfrag = Bf2;
        if (i >= 1152 * 128) return;
    }
    int kp = i >> 7, n = i & 127;
    float v;
    if (kp < 1024) {
        int d = kp >> 3, r = kp & 7;
        v = W[((size_t)r * 128 + d) * 128 + n];
    } else {
        v = root[(size_t)(kp - 1024) * 128 + n];
    }
    int kb = kp >> 5;
    int lane = (((kp >> 3) & 3) << 4) | (n & 15);
    int j = kp & 7;
    int t = n >> 4;
    Bfrag[(((size_t)(kb * 8 + t) * 64 + lane) << 3) + j] = f2bf(v);
}

// ---------------------------------------------------------------------------
// CSR build
// ---------------------------------------------------------------------------
__global__ void zero_i32(int* __restrict__ p, int n) {
    int i = blockIdx.x * 256 + threadIdx.x;
    if (i < n) p[i] = 0;
}

__global__ void hist_dst(const int* __restrict__ ei, int* __restrict__ cnt, int E) {
    int e = blockIdx.x * 256 + threadIdx.x;
    if (e >= E) return;
    atomicAdd(&cnt[ei[E + e]], 1);
}

__global__ void scan1(const int* __restrict__ cnt, int* __restrict__ part,
                      int* __restrict__ bsum, int N) {
    int i = blockIdx.x * 256 + threadIdx.x;
    int v = (i < N) ? cnt[i] : 0;
    int lane = threadIdx.x & 63, wid = threadIdx.x >> 6;
    int s = v;
    #pragma unroll
    for (int off = 1; off < 64; off <<= 1) {
        int t = __shfl_up(s, off);
        if (lane >= off) s += t;
    }
    __shared__ int wsum[4];
    if (lane == 63) wsum[wid] = s;
    __syncthreads();
    int add = 0;
    for (int w = 0; w < wid; ++w) add += wsum[w];
    s += add;
    part[i] = s - v;
    if (threadIdx.x == 255) bsum[blockIdx.x] = s;
}

__global__ void scan2(int* __restrict__ bsum, int nb) {
    int i = threadIdx.x;
    int v = (i < nb) ? bsum[i] : 0;
    int lane = threadIdx.x & 63, wid = threadIdx.x >> 6;
    int s = v;
    #pragma unroll
    for (int off = 1; off < 64; off <<= 1) {
        int t = __shfl_up(s, off);
        if (lane >= off) s += t;
    }
    __shared__ int wsum[4];
    if (lane == 63) wsum[wid] = s;
    __syncthreads();
    int add = 0;
    for (int w = 0; w < wid; ++w) add += wsum[w];
    s += add;
    if (i < nb) bsum[i] = s - v;
}

__global__ void scan3(const int* __restrict__ part, const int* __restrict__ bsum,
                      int* __restrict__ rowptr, int* __restrict__ woff, int N) {
    int i = blockIdx.x * 256 + threadIdx.x;
    if (i >= N) return;
    int v = part[i] + bsum[blockIdx.x];
    rowptr[i] = v;
    woff[i] = v;
}

// eattr stored bf16-packed: 8 relations -> 16B per edge
__global__ void scatter_edges(const int* __restrict__ ei, const float4* __restrict__ attr,
                              int* __restrict__ woff, int* __restrict__ esrc,
                              short8* __restrict__ eattr, int E) {
    int e = blockIdx.x * 256 + threadIdx.x;
    if (e >= E) return;
    int src = ei[e], dst = ei[E + e];
    float4 a0 = attr[2 * e], a1 = attr[2 * e + 1];
    short8 pk;
    pk[0] = (short)f2bf(a0.x); pk[1] = (short)f2bf(a0.y);
    pk[2] = (short)f2bf(a0.z); pk[3] = (short)f2bf(a0.w);
    pk[4] = (short)f2bf(a1.x); pk[5] = (short)f2bf(a1.y);
    pk[6] = (short)f2bf(a1.z); pk[7] = (short)f2bf(a1.w);
    int p = atomicAdd(&woff[dst], 1);
    esrc[p] = src;
    eattr[p] = pk;
}

// ---------------------------------------------------------------------------
// LN + GELU on x (fp32 in) -> A tail cols 1024..1151 (bf16). One wave per row.
// ---------------------------------------------------------------------------
__global__ void ln_gelu(const float* __restrict__ x, const float* __restrict__ g,
                        const float* __restrict__ b, unsigned short* __restrict__ A, int N) {
    int row = (blockIdx.x * blockDim.x + threadIdx.x) >> 6;
    if (row >= N) return;
    int lane = threadIdx.x & 63;
    float2 v = *(const float2*)(x + (size_t)row * 128 + lane * 2);
    float s = v.x + v.y;
    #pragma unroll
    for (int o = 32; o; o >>= 1) s += __shfl_xor(s, o);
    float mu = s * (1.0f / 128.0f);
    float d0 = v.x - mu, d1 = v.y - mu;
    float q = d0 * d0 + d1 * d1;
    #pragma unroll
    for (int o = 32; o; o >>= 1) q += __shfl_xor(q, o);
    float rs = rsqrtf(q * (1.0f / 128.0f) + 1e-5f);
    float2 gg = *(const float2*)(g + lane * 2);
    float2 bb = *(const float2*)(b + lane * 2);
    ushort2 o2;
    o2.x = f2bf(gelu_exact(d0 * rs * gg.x + bb.x));
    o2.y = f2bf(gelu_exact(d1 * rs * gg.y + bb.y));
    *(ushort2*)(A + (size_t)row * LDA + 1024 + lane * 2) = o2;
}

// ---------------------------------------------------------------------------
// Edge aggregation into A cols 0..1023 (k'-ordered). One wave per dst node;
// gathers y from A tail. Unrolled x4 (4 gathers in flight). bf16 eattr.
// ---------------------------------------------------------------------------
__global__ __launch_bounds__(256) void edge_z(const int* __restrict__ rowptr,
                                              const int* __restrict__ esrc,
                                              const short8* __restrict__ eattr,
                                              unsigned short* __restrict__ A, int N, int E) {
    int row = (blockIdx.x << 2) + (threadIdx.x >> 6);
    if (row >= N) return;
    int lane = threadIdx.x & 63;
    int e0 = rowptr[row];
    int e1 = (row + 1 < N) ? rowptr[row + 1] : E;
    float a0[8] = {0,0,0,0,0,0,0,0};
    float a1[8] = {0,0,0,0,0,0,0,0};
    const unsigned short* yl = A + 1024 + lane * 2;

    #define EDGE_FMA(hv, ea) do {                                      \
        float y0 = bf2f((unsigned short)((hv) & 0xffffu));             \
        float y1 = bf2f((unsigned short)((hv) >> 16));                 \
        _Pragma("unroll")                                              \
        for (int r = 0; r < 8; ++r) {                                  \
            float wv = bf2f((unsigned short)(ea)[r]);                  \
            a0[r] += wv * y0; a1[r] += wv * y1;                        \
        }                                                              \
    } while (0)

    int e = e0;
    for (; e + 4 <= e1; e += 4) {
        unsigned int h[4];
        short8 ea[4];
        #pragma unroll
        for (int u = 0; u < 4; ++u) {
            h[u] = *(const unsigned int*)(yl + (size_t)esrc[e + u] * LDA);
            ea[u] = eattr[e + u];
        }
        #pragma unroll
        for (int u = 0; u < 4; ++u) EDGE_FMA(h[u], ea[u]);
    }
    for (; e < e1; ++e) {
        unsigned int h = *(const unsigned int*)(yl + (size_t)esrc[e] * LDA);
        short8 ea = eattr[e];
        EDGE_FMA(h, ea);
    }
    #undef EDGE_FMA

    short8 p0, p1;
    #pragma unroll
    for (int r = 0; r < 8; ++r) { p0[r] = (short)f2bf(a0[r]); p1[r] = (short)f2bf(a1[r]); }
    unsigned short* zr = A + (size_t)row * LDA + lane * 16;
    *(short8*)zr = p0;
    *(short8*)(zr + 8) = p1;
}

// ---------------------------------------------------------------------------
// GEMM v5: A (N x 1152 bf16) @ B (1152 x 128) — occupancy-first.
// Block = 256 threads (4 waves) = 128 rows; wave = 32 rows x 128 cols.
// B staged in 16KB chunks (2 kb-steps) double-buffered in LDS (32KB/block)
// via global_load_lds -> up to 4 blocks/CU co-resident; barrier drains of one
// block overlap with MFMA/loads of the others. Grid = 391 blocks.
// MODE 0: gelu(LN(C+bias)) -> bf16 into A tail (own rows only).
// MODE 1: C+bias+xres -> fp32 out [N][128].
// ---------------------------------------------------------------------------
template <int MODE>
__global__ __launch_bounds__(256) void gemm_fused(
        unsigned short* __restrict__ A, const unsigned short* __restrict__ Bfrag,
        const float* __restrict__ bias, const float* __restrict__ lng,
        const float* __restrict__ lnb, const float* __restrict__ xres,
        float* __restrict__ outp, int N) {
    __shared__ short8 Bs[2][1024];   // 2 x 16 KB

    int w = threadIdx.x >> 6;        // 0..3
    int lane = threadIdx.x & 63;
    int l15 = lane & 15, lhi = lane >> 4;
    int m0 = blockIdx.x * 128 + w * 32;

    const unsigned short* a0p = A + (size_t)(m0 + l15) * LDA + lhi * 8;
    const unsigned short* a1p = a0p + 16 * LDA;
    const short8* bfb = (const short8*)Bfrag;

    // stage chunk c (kb = 2c, 2c+1) = 1024 short8 = 16KB; 4 gload_lds per thread
    #define STAGE(buf, c)                                                          \
        do {                                                                       \
            const short8* gsrc = bfb + (size_t)(c) * 1024 + w * 64;                \
            _Pragma("unroll")                                                      \
            for (int i = 0; i < 4; ++i)                                            \
                __builtin_amdgcn_global_load_lds(&gsrc[i * 256 + lane],            \
                                                 &Bs[buf][w * 64 + i * 256], 16, 0, 0); \
        } while (0)

    STAGE(0, 0);
    short8 af0[2], af1[2];
    #pragma unroll
    for (int k = 0; k < 2; ++k) {
        af0[k] = *(const short8*)(a0p + k * 32);
        af1[k] = *(const short8*)(a1p + k * 32);
    }
    __syncthreads();

    f32x4 acc0[8] = {}, acc1[8] = {};
    for (int c = 0; c < 18; ++c) {
        int cur = c & 1;
        if (c < 17) STAGE(cur ^ 1, c + 1);
        #pragma unroll
        for (int k = 0; k < 2; ++k) {
            #pragma unroll
            for (int t = 0; t < 8; ++t) {
                short8 b = Bs[cur][k * 512 + t * 64 + lane];
                acc0[t] = __builtin_amdgcn_mfma_f32_16x16x32_bf16(af0[k], b, acc0[t], 0, 0, 0);
                acc1[t] = __builtin_amdgcn_mfma_f32_16x16x32_bf16(af1[k], b, acc1[t], 0, 0, 0);
            }
        }
        if (c < 17) {
            #pragma unroll
            for (int k = 0; k < 2; ++k) {
                af0[k] = *(const short8*)(a0p + ((c + 1) * 2 + k) * 32);
                af1[k] = *(const short8*)(a1p + ((c + 1) * 2 + k) * 32);
            }
            __syncthreads();
        }
    }
    #undef STAGE

    float bcol[8];
    #pragma unroll
    for (int t = 0; t < 8; ++t) bcol[t] = bias[t * 16 + l15];

    if (MODE == 0) {
        float gcol[8], lbcol[8];
        #pragma unroll
        for (int t = 0; t < 8; ++t) { gcol[t] = lng[t * 16 + l15]; lbcol[t] = lnb[t * 16 + l15]; }
        #pragma unroll
        for (int g = 0; g < 2; ++g) {
            int mb = m0 + g * 16;
            #pragma unroll
            for (int reg = 0; reg < 4; ++reg) {
                int row = mb + lhi * 4 + reg;
                float tv[8];
                float s = 0.f;
                #pragma unroll
                for (int t = 0; t < 8; ++t) {
                    tv[t] = (g ? acc1[t][reg] : acc0[t][reg]) + bcol[t];
                    s += tv[t];
                }
                #pragma unroll
                for (int msk = 1; msk < 16; msk <<= 1) s += __shfl_xor(s, msk);
                float mu = s * (1.0f / 128.0f);
                float q = 0.f;
                #pragma unroll
                for (int t = 0; t < 8; ++t) { float d = tv[t] - mu; q += d * d; }
                #pragma unroll
                for (int msk = 1; msk < 16; msk <<= 1) q += __shfl_xor(q, msk);
                float rs = rsqrtf(q * (1.0f / 128.0f) + 1e-5f);
                if (row < N) {
                    #pragma unroll
                    for (int t = 0; t < 8; ++t) {
                        float u = gelu_exact((tv[t] - mu) * rs * gcol[t] + lbcol[t]);
                        A[(size_t)row * LDA + 1024 + t * 16 + l15] = f2bf(u);
                    }
                }
            }
        }
    } else {
        #pragma unroll
        for (int g = 0; g < 2; ++g) {
            int mb = m0 + g * 16;
            #pragma unroll
            for (int reg = 0; reg < 4; ++reg) {
                int row = mb + lhi * 4 + reg;
                if (row < N) {
                    #pragma unroll
                    for (int t = 0; t < 8; ++t) {
                        size_t idx = (size_t)row * 128 + t * 16 + l15;
                        outp[idx] = (g ? acc1[t][reg] : acc0[t][reg]) + bcol[t] + xres[idx];
                    }
                }
            }
        }
    }
}

extern "C" void kernel_launch(void* const* d_in, const int* in_sizes, int n_in,
                              void* d_out, int out_size, void* d_ws, size_t ws_size,
                              hipStream_t stream) {
    const float* x     = (const float*)d_in[0];
    const int*   ei    = (const int*)d_in[1];
    const float* attr  = (const float*)d_in[2];
    const float* ln1g  = (const float*)d_in[3];
    const float* ln1b  = (const float*)d_in[4];
    const float* W1    = (const float*)d_in[5];
    const float* root1 = (const float*)d_in[6];
    const float* b1    = (const float*)d_in[7];
    const float* ln2g  = (const float*)d_in[8];
    const float* ln2b  = (const float*)d_in[9];
    const float* W2    = (const float*)d_in[10];
    const float* root2 = (const float*)d_in[11];
    const float* b2    = (const float*)d_in[12];

    const int N = in_sizes[0] / 128;   // 50000
    const int E = in_sizes[1] / 2;     // 600000

    // workspace layout; A padded to 50048 rows (391 blocks x 128) for OOB-safe
    // A-frag reads in the last GEMM block. 50048*1152*2 = 115,310,592 B.
    char* ws = (char*)d_ws;
    unsigned short* A     = (unsigned short*)(ws);                    // 115,310,592
    unsigned short* Bf1   = (unsigned short*)(ws + 115400000);        // 294,912
    unsigned short* Bf2   = (unsigned short*)(ws + 115700000);        // 294,912
    int*            cnt   = (int*)(ws + 116000000);                   // 200,704
    int*            part  = (int*)(ws + 116210000);                   // 200,704
    int*            bsum  = (int*)(ws + 116420000);                   // 1,024
    int*            rowptr= (int*)(ws + 116430000);                   // 200,000
    int*            woff  = (int*)(ws + 116640000);                   // 200,000
    int*            esrc  = (int*)(ws + 116850000);                   // 2,400,000
    short8*         eattr = (short8*)(ws + 119250000);                // 9,600,000

    const int scanBlocks  = (N + 255) / 256;               // 196
    const int edgeBlocksE = (E + 255) / 256;               // 2344
    const int rowsBlocks  = (N * 64 + 255) / 256;          // 12500
    const int nodeBlocks  = (N + 3) / 4;                   // 12500
    const int gemmBlocks  = (N + 127) / 128;               // 391

    // weights -> fragment order (both layers, one launch)
    prep_w<<<1152, 256, 0, stream>>>(W1, root1, Bf1, W2, root2, Bf2);

    // CSR build (by dst)
    zero_i32<<<scanBlocks, 256, 0, stream>>>(cnt, scanBlocks * 256);
    hist_dst<<<edgeBlocksE, 256, 0, stream>>>(ei, cnt, E);
    scan1<<<scanBlocks, 256, 0, stream>>>(cnt, part, bsum, N);
    scan2<<<1, 256, 0, stream>>>(bsum, scanBlocks);
    scan3<<<scanBlocks, 256, 0, stream>>>(part, bsum, rowptr, woff, N);
    scatter_edges<<<edgeBlocksE, 256, 0, stream>>>(ei, (const float4*)attr, woff, esrc, eattr, E);

    // ---- layer 1 ----
    ln_gelu<<<rowsBlocks, 256, 0, stream>>>(x, ln1g, ln1b, A, N);
    edge_z<<<nodeBlocks, 256, 0, stream>>>(rowptr, esrc, eattr, A, N, E);
    gemm_fused<0><<<gemmBlocks, 256, 0, stream>>>(A, Bf1, b1, ln2g, ln2b, nullptr, nullptr, N);

    // ---- layer 2 ----
    edge_z<<<nodeBlocks, 256, 0, stream>>>(rowptr, esrc, eattr, A, N, E);
    gemm_fused<1><<<gemmBlocks, 256, 0, stream>>>(A, Bf2, b2, nullptr, nullptr, x, (float*)d_out, N);
}